// Round 3
// baseline (933.628 us; speedup 1.0000x reference)
//
#include <hip/hip_runtime.h>
#include <hip/hip_bf16.h>
#include <math.h>

#define B_  16
#define T_  1024
#define D_  768
#define S_  64
#define H_  8
#define DH_ 96
#define FF_ 3072
#define TD_ 512
#define V_  49408
#define M_  1024  // B_*S_

typedef __bf16 bf16_8 __attribute__((ext_vector_type(8)));
typedef __bf16 bf16x4 __attribute__((ext_vector_type(4)));
typedef float f32x4 __attribute__((ext_vector_type(4)));

__device__ __forceinline__ void async16(const void* g, void* lds) {
  __builtin_amdgcn_global_load_lds((const __attribute__((address_space(1))) void*)g,
                                   (__attribute__((address_space(3))) void*)lds,
                                   16, 0, 0);
}

__device__ __forceinline__ float blk_sum256(float v, float* red) {
#pragma unroll
  for (int o = 32; o > 0; o >>= 1) v += __shfl_down(v, o, 64);
  const int w = threadIdx.x >> 6;
  if ((threadIdx.x & 63) == 0) red[w] = v;
  __syncthreads();
  float t = red[0] + red[1] + red[2] + red[3];
  __syncthreads();
  return t;
}

// ---------------- GEMM: C[M,N] = A[M,K](bf16) * B[N,K]^T(bf16), fp32 acc ----------
// MODE 0: fp32 out (+bias)  1: relu bf16 out (+bias)  2: exp bf16 out + fused rowsum
// MODE 3: atomicAdd fp32
template <int MODE>
__global__ __launch_bounds__(256, 2) void gemm_nt(
    const __bf16* __restrict__ A, const __bf16* __restrict__ Bm,
    const float* __restrict__ bias, void* __restrict__ Cv,
    float* __restrict__ rsum, int Nr, int Kr, int kIterPerZ) {
  __shared__ __bf16 Als[128 * 32];
  __shared__ __bf16 Bls[128 * 32];
  const int tid = threadIdx.x;
  const int w = tid >> 6, l = tid & 63;
  const int m0 = blockIdx.x * 128, n0 = blockIdx.y * 128;
  const int totIt = Kr >> 5;
  const int it0 = blockIdx.z * kIterPerZ;
  const int nIt = min(kIterPerZ, totIt - it0);
  if (nIt <= 0) return;

  const int i0 = w * 128 + l, i1 = i0 + 64;
  const int ra0 = i0 >> 2, ca0 = ((i0 & 3) ^ ((i0 >> 3) & 3)) * 8;
  const int ra1 = i1 >> 2, ca1 = ((i1 & 3) ^ ((i1 >> 3) & 3)) * 8;
  const __bf16* gA0 = A + (size_t)(m0 + ra0) * Kr + ca0;
  const __bf16* gA1 = A + (size_t)(m0 + ra1) * Kr + ca1;
  const __bf16* gB0 = Bm + (size_t)(n0 + ra0) * Kr + ca0;
  const __bf16* gB1 = Bm + (size_t)(n0 + ra1) * Kr + ca1;
  __bf16* lA0 = &Als[(w * 128 + 0) * 8];
  __bf16* lA1 = &Als[(w * 128 + 64) * 8];
  __bf16* lB0 = &Bls[(w * 128 + 0) * 8];
  __bf16* lB1 = &Bls[(w * 128 + 64) * 8];

  const int wm = (w & 1) * 64, wn = (w >> 1) * 64;
  const int frow = l & 15, fq = l >> 4;
  const int fc = (fq ^ ((frow >> 1) & 3)) * 8;

  f32x4 acc[4][4];
  const f32x4 zero = {0.f, 0.f, 0.f, 0.f};
#pragma unroll
  for (int a = 0; a < 4; ++a)
#pragma unroll
    for (int b = 0; b < 4; ++b) acc[a][b] = zero;

  for (int it = 0; it < nIt; ++it) {
    const size_t k0 = (size_t)(it0 + it) << 5;
    __syncthreads();
    async16(gA0 + k0, lA0);
    async16(gA1 + k0, lA1);
    async16(gB0 + k0, lB0);
    async16(gB1 + k0, lB1);
    __syncthreads();
    bf16_8 af[4], bf[4];
#pragma unroll
    for (int mi = 0; mi < 4; ++mi)
      af[mi] = *(const bf16_8*)&Als[(wm + mi * 16 + frow) * 32 + fc];
#pragma unroll
    for (int ni = 0; ni < 4; ++ni)
      bf[ni] = *(const bf16_8*)&Bls[(wn + ni * 16 + frow) * 32 + fc];
#pragma unroll
    for (int mi = 0; mi < 4; ++mi)
#pragma unroll
      for (int ni = 0; ni < 4; ++ni)
        acc[mi][ni] = __builtin_amdgcn_mfma_f32_16x16x32_bf16(af[mi], bf[ni], acc[mi][ni], 0, 0, 0);
  }

  if (MODE == 2) {
#pragma unroll
    for (int mi = 0; mi < 4; ++mi) {
#pragma unroll
      for (int r = 0; r < 4; ++r) {
        const int row = m0 + wm + mi * 16 + fq * 4 + r;
        float partial = 0.f;
#pragma unroll
        for (int ni = 0; ni < 4; ++ni) {
          const int col = n0 + wn + ni * 16 + frow;
          const __bf16 h = (__bf16)exp2f(acc[mi][ni][r] * 1.4426950408889634f);
          ((__bf16*)Cv)[(size_t)row * Nr + col] = h;
          partial += (float)h;
        }
#pragma unroll
        for (int off = 1; off < 16; off <<= 1) partial += __shfl_xor(partial, off, 64);
        if (frow == 0) atomicAdd(&rsum[row], partial);
      }
    }
    return;
  }

#pragma unroll
  for (int mi = 0; mi < 4; ++mi) {
#pragma unroll
    for (int r = 0; r < 4; ++r) {
      const int row = m0 + wm + mi * 16 + fq * 4 + r;
#pragma unroll
      for (int ni = 0; ni < 4; ++ni) {
        const int col = n0 + wn + ni * 16 + frow;
        float v = acc[mi][ni][r];
        if (MODE == 0) {
          if (bias) v += bias[col];
          ((float*)Cv)[(size_t)row * Nr + col] = v;
        } else if (MODE == 1) {
          v += bias[col];
          ((__bf16*)Cv)[(size_t)row * Nr + col] = (__bf16)fmaxf(v, 0.f);
        } else {
          atomicAdd(&((float*)Cv)[(size_t)row * Nr + col], v);
        }
      }
    }
  }
}

// -------- transpose fp32 [R][C] -> bf16 [C][R] (weights) --------------------------
__global__ __launch_bounds__(256) void transpose_bf16k(const float* __restrict__ src,
                                                       __bf16* __restrict__ dst, int R, int C) {
  __shared__ float tl[32][33];
  const int tx = threadIdx.x & 31, ty = threadIdx.x >> 5;
  const int c0 = blockIdx.x * 32, r0 = blockIdx.y * 32;
#pragma unroll
  for (int k = 0; k < 4; ++k) {
    int r = ty + k * 8;
    tl[r][tx] = src[(size_t)(r0 + r) * C + (c0 + tx)];
  }
  __syncthreads();
#pragma unroll
  for (int k = 0; k < 4; ++k) {
    int r = ty + k * 8;
    dst[(size_t)(c0 + r) * R + (r0 + tx)] = (__bf16)tl[tx][r];
  }
}

__global__ __launch_bounds__(256) void concat_bias_k(const float* __restrict__ bq,
                                                     const float* __restrict__ bk,
                                                     const float* __restrict__ bv,
                                                     float* __restrict__ dst) {
  int i = blockIdx.x * 256 + threadIdx.x;
  if (i < 768) dst[i] = bq[i];
  else if (i < 1536) dst[i] = bk[i - 768];
  else if (i < 2304) dst[i] = bv[i - 1536];
}

// -------- emb prep: read fp32 emb once, write normalized bf16 + raw transpose -----
__global__ __launch_bounds__(256) void embprep_k(const float* __restrict__ emb,
                                                 __bf16* __restrict__ embn,
                                                 __bf16* __restrict__ embT, int nc) {
  __shared__ __bf16 tile[32][516];
  const int tid = threadIdx.x;
  const int r = tid >> 4, i = tid & 15;
  const int vloc = blockIdx.x * 32;
  float4 f[2][8];
  float ss[2] = {0.f, 0.f};
#pragma unroll
  for (int h = 0; h < 2; ++h) {
    const int v = vloc + r + h * 16;
    const float4* row = (const float4*)(emb + (size_t)v * 512);
#pragma unroll
    for (int j = 0; j < 8; ++j) {
      float4 x = row[i + j * 16];
      f[h][j] = x;
      ss[h] += x.x * x.x + x.y * x.y + x.z * x.z + x.w * x.w;
    }
  }
#pragma unroll
  for (int off = 1; off < 16; off <<= 1) {
    ss[0] += __shfl_xor(ss[0], off, 64);
    ss[1] += __shfl_xor(ss[1], off, 64);
  }
  float inv[2];
#pragma unroll
  for (int h = 0; h < 2; ++h) inv[h] = 1.f / fmaxf(sqrtf(ss[h]), 1e-8f);
#pragma unroll
  for (int h = 0; h < 2; ++h) {
    const int vr = r + h * 16;
#pragma unroll
    for (int j = 0; j < 8; ++j) {
      const int d4 = i + j * 16;
      float4 x = f[h][j];
      tile[vr][d4 * 4 + 0] = (__bf16)x.x;
      tile[vr][d4 * 4 + 1] = (__bf16)x.y;
      tile[vr][d4 * 4 + 2] = (__bf16)x.z;
      tile[vr][d4 * 4 + 3] = (__bf16)x.w;
      bf16x4 o;
      o[0] = (__bf16)(x.x * inv[h]);
      o[1] = (__bf16)(x.y * inv[h]);
      o[2] = (__bf16)(x.z * inv[h]);
      o[3] = (__bf16)(x.w * inv[h]);
      *(bf16x4*)(embn + (size_t)(vloc + vr) * 512 + d4 * 4) = o;
    }
  }
  __syncthreads();
#pragma unroll
  for (int c = 0; c < 2; ++c) {
    const int d = tid + c * 256;
    uint us[16];
#pragma unroll
    for (int v = 0; v < 32; v += 2) {
      __bf16 a = tile[v][d], b = tile[v + 1][d];
      us[v >> 1] = (uint)(*(unsigned short*)&a) | ((uint)(*(unsigned short*)&b) << 16);
    }
    uint4* dst = (uint4*)(embT + (size_t)d * nc + vloc);
#pragma unroll
    for (int q = 0; q < 4; ++q) {
      uint4 u = {us[q * 4], us[q * 4 + 1], us[q * 4 + 2], us[q * 4 + 3]};
      dst[q] = u;
    }
  }
}

// -------- segment pooling phase 1: chunked streaming partial sums (atomics) -------
__global__ __launch_bounds__(256) void seg_partial_k(
    const float* __restrict__ af, const int* __restrict__ align,
    const int* __restrict__ alen, float* __restrict__ srcsum) {
  __shared__ int ts_s[64], te_s[64], segid[64];
  const int b = blockIdx.x, ch = blockIdx.y;
  const int tid = threadIdx.x;
  if (tid < 64) {
    const int ts = align[(b * 64 + tid) * 2];
    const int te = align[(b * 64 + tid) * 2 + 1];
    const int teff = (te == alen[b]) ? T_ : te;
    ts_s[tid] = min(max(ts, 0), T_);
    te_s[tid] = min(max(teff, 0), T_);
  }
  __syncthreads();
  const int t0 = ch * 64;
  if (tid < 64) {
    const int t = t0 + tid;
    int s = -1;
    if (ts_s[0] <= t) {
      int lo = 0, hi = 63;
      while (lo < hi) {
        const int mid = (lo + hi + 1) >> 1;
        if (ts_s[mid] <= t) lo = mid; else hi = mid - 1;
      }
      s = (t < te_s[lo]) ? lo : -1;
    }
    segid[tid] = s;
  }
  __syncthreads();
  float a0 = 0.f, a1 = 0.f, a2 = 0.f;
  int cur = -1;
  for (int k = 0; k < 64; ++k) {
    const int s = segid[k];
    if (s != cur) {
      if (cur >= 0) {
        float* dst = srcsum + (size_t)(b * 64 + cur) * 768 + tid;
        atomicAdd(dst, a0); atomicAdd(dst + 256, a1); atomicAdd(dst + 512, a2);
      }
      a0 = a1 = a2 = 0.f;
      cur = s;
    }
    if (s >= 0) {
      const float* row = af + ((size_t)b * T_ + t0 + k) * 768 + tid;
      a0 += row[0]; a1 += row[256]; a2 += row[512];
    }
  }
  if (cur >= 0) {
    float* dst = srcsum + (size_t)(b * 64 + cur) * 768 + tid;
    atomicAdd(dst, a0); atomicAdd(dst + 256, a1); atomicAdd(dst + 512, a2);
  }
}

// -------- segment pooling phase 2: mean + mask + LayerNorm ------------------------
__global__ __launch_bounds__(256) void pool_fin_k(
    const float* __restrict__ srcsum, const int* __restrict__ align,
    const int* __restrict__ alen, const int* __restrict__ anum,
    const float* __restrict__ g, const float* __restrict__ be,
    float* __restrict__ srcf, __bf16* __restrict__ srcb) {
  __shared__ float red[4];
  const int m = blockIdx.x, b = m >> 6, s = m & 63;
  const int tid = threadIdx.x;
  const int ts = align[m * 2], te = align[m * 2 + 1];
  const bool valid = (ts >= 0) && (s < anum[b]);
  const int teff = (te == alen[b]) ? T_ : te;
  const int tsc = min(max(ts, 0), T_), tec = min(max(teff, 0), T_);
  const float invc = 1.f / (float)max(tec - tsc, 1);
  float x[3];
#pragma unroll
  for (int u = 0; u < 3; ++u) {
    const int d = tid + u * 256;
    x[u] = valid ? srcsum[(size_t)m * 768 + d] * invc : 0.f;
  }
  const float mean = blk_sum256(x[0] + x[1] + x[2], red) * (1.f / 768.f);
  float lv = 0.f;
#pragma unroll
  for (int u = 0; u < 3; ++u) { float dd = x[u] - mean; lv += dd * dd; }
  const float var = blk_sum256(lv, red) * (1.f / 768.f);
  const float rstd = rsqrtf(var + 1e-5f);
#pragma unroll
  for (int u = 0; u < 3; ++u) {
    const int d = tid + u * 256;
    const float o = (x[u] - mean) * rstd * g[d] + be[d];
    srcf[(size_t)m * 768 + d] = o;
    srcb[(size_t)m * 768 + d] = (__bf16)o;
  }
}

// -------- residual add + LayerNorm ------------------------------------------------
__global__ __launch_bounds__(256) void add_ln_k(
    const float* __restrict__ a, const float* __restrict__ r,
    const float* __restrict__ g, const float* __restrict__ be,
    float* __restrict__ outf, __bf16* __restrict__ outb) {
  __shared__ float red[4];
  const int m = blockIdx.x, tid = threadIdx.x;
  float x[3];
#pragma unroll
  for (int u = 0; u < 3; ++u) {
    const size_t idx = (size_t)m * 768 + tid + u * 256;
    x[u] = a[idx] + (r ? r[idx] : 0.f);
  }
  const float mean = blk_sum256(x[0] + x[1] + x[2], red) * (1.f / 768.f);
  float lv = 0.f;
#pragma unroll
  for (int u = 0; u < 3; ++u) { float dd = x[u] - mean; lv += dd * dd; }
  const float var = blk_sum256(lv, red) * (1.f / 768.f);
  const float rstd = rsqrtf(var + 1e-5f);
#pragma unroll
  for (int u = 0; u < 3; ++u) {
    const int d = tid + u * 256;
    const float o = (x[u] - mean) * rstd * g[d] + be[d];
    if (outf) outf[(size_t)m * 768 + d] = o;
    if (outb) outb[(size_t)m * 768 + d] = (__bf16)o;
  }
}

// -------- attention: one block per (b,h) ------------------------------------------
__global__ __launch_bounds__(256) void attn_k(const float* __restrict__ qkv,
                                              const int* __restrict__ anum,
                                              __bf16* __restrict__ ctx) {
  __shared__ __bf16 qb[64 * 96], kb[64 * 96], vb[64 * 96];
  __shared__ float sc[64 * 66];
  const int tid = threadIdx.x;
  const int b = blockIdx.x >> 3, h = blockIdx.x & 7;
  const int colq = h * 96;
  for (int idx = tid; idx < 6144; idx += 256) {
    const int s = idx / 96, d = idx - s * 96;
    const size_t base = ((size_t)(b * 64 + s)) * 2304 + colq + d;
    qb[idx] = (__bf16)qkv[base];
    kb[idx] = (__bf16)qkv[base + 768];
    vb[idx] = (__bf16)qkv[base + 1536];
  }
  __syncthreads();
  const int i = tid >> 2, jg = tid & 3;
  for (int jj = 0; jj < 16; ++jj) {
    const int j = jg * 16 + jj;
    float dot = 0.f;
    for (int d = 0; d < 96; ++d) dot += (float)qb[i * 96 + d] * (float)kb[j * 96 + d];
    sc[i * 66 + j] = dot * 0.10206207261596577f;  // 1/sqrt(96)
  }
  __syncthreads();
  if (tid < 64) {
    const int an = anum[b];
    float mx = -3.4e38f;
    for (int j = 0; j < 64; ++j) {
      float v = (j < an) ? sc[tid * 66 + j] : -1e30f;
      sc[tid * 66 + j] = v;
      mx = fmaxf(mx, v);
    }
    float sum = 0.f;
    for (int j = 0; j < 64; ++j) {
      float e = exp2f((sc[tid * 66 + j] - mx) * 1.4426950408889634f);
      sc[tid * 66 + j] = e;
      sum += e;
    }
    const float inv = 1.f / sum;
    for (int j = 0; j < 64; ++j) sc[tid * 66 + j] *= inv;
  }
  __syncthreads();
  const int dg = tid & 3;
  for (int dd = 0; dd < 24; ++dd) {
    const int d = dg * 24 + dd;
    float s2 = 0.f;
    for (int j = 0; j < 64; ++j) s2 += sc[i * 66 + j] * (float)vb[j * 96 + d];
    ctx[((size_t)(b * 64 + i)) * 768 + colq + d] = (__bf16)s2;
  }
}

// -------- row L2-normalize (512-wide) fp32 -> bf16 (for kw) -----------------------
__global__ __launch_bounds__(256) void l2norm_bf16_k(const float* __restrict__ src,
                                                     __bf16* __restrict__ dst) {
  __shared__ float red[4];
  const int rix = blockIdx.x, tid = threadIdx.x;
  const float* row = src + (size_t)rix * 512;
  const float v0 = row[tid], v1 = row[tid + 256];
  const float tot = blk_sum256(v0 * v0 + v1 * v1, red);
  const float inv = 1.f / fmaxf(sqrtf(tot), 1e-8f);
  dst[(size_t)rix * 512 + tid] = (__bf16)(v0 * inv);
  dst[(size_t)rix * 512 + tid + 256] = (__bf16)(v1 * inv);
}

__global__ __launch_bounds__(256) void final_scale_k(const float* __restrict__ acc,
                                                     const float* __restrict__ rs,
                                                     float* __restrict__ out) {
  const int m = blockIdx.x, d = threadIdx.x;
  const float inv = 1.f / rs[m];
  out[(size_t)m * 512 + d] = acc[(size_t)m * 512 + d] * inv;
  out[(size_t)m * 512 + d + 256] = acc[(size_t)m * 512 + d + 256] * inv;
}

extern "C" void kernel_launch(void* const* d_in, const int* in_sizes, int n_in,
                              void* d_out, int out_size, void* d_ws, size_t ws_size,
                              hipStream_t stream) {
  const float* audio = (const float*)d_in[0];
  const float* ln1g = (const float*)d_in[1];
  const float* ln1b = (const float*)d_in[2];
  const float* wq = (const float*)d_in[3];
  const float* bq = (const float*)d_in[4];
  const float* wk = (const float*)d_in[5];
  const float* bk = (const float*)d_in[6];
  const float* wv = (const float*)d_in[7];
  const float* bv = (const float*)d_in[8];
  const float* wo = (const float*)d_in[9];
  const float* bo = (const float*)d_in[10];
  const float* lnag = (const float*)d_in[11];
  const float* lnab = (const float*)d_in[12];
  const float* w1 = (const float*)d_in[13];
  const float* b1 = (const float*)d_in[14];
  const float* w2 = (const float*)d_in[15];
  const float* b2 = (const float*)d_in[16];
  const float* lnbg = (const float*)d_in[17];
  const float* lnbb = (const float*)d_in[18];
  const float* wp = (const float*)d_in[19];
  const float* bp = (const float*)d_in[20];
  const float* emb = (const float*)d_in[21];
  const int* alen = (const int*)d_in[22];
  const int* align = (const int*)d_in[23];
  const int* anum = (const int*)d_in[24];
  float* out = (float*)d_out;

  char* p = (char*)d_ws;
  auto alloc = [&](size_t bytes) {
    char* r = p;
    p += (bytes + 255) & ~(size_t)255;
    return r;
  };
  float* srcsum = (float*)alloc((size_t)M_ * 768 * 4);
  float* srcf = (float*)alloc((size_t)M_ * 768 * 4);
  __bf16* srcb = (__bf16*)alloc((size_t)M_ * 768 * 2);
  float* qkv = (float*)alloc((size_t)M_ * 2304 * 4);
  __bf16* ctxb = (__bf16*)alloc((size_t)M_ * 768 * 2);
  float* ybuf = (float*)alloc((size_t)M_ * 768 * 4);
  float* xf = (float*)alloc((size_t)M_ * 768 * 4);
  __bf16* xb = (__bf16*)alloc((size_t)M_ * 768 * 2);
  __bf16* hb = (__bf16*)alloc((size_t)M_ * FF_ * 2);
  __bf16* x2b = (__bf16*)alloc((size_t)M_ * 768 * 2);
  float* kw = (float*)alloc((size_t)M_ * 512 * 4);
  __bf16* kwn = (__bf16*)alloc((size_t)M_ * 512 * 2);
  float* kwacc = (float*)alloc((size_t)M_ * 512 * 4);
  float* rs = (float*)alloc((size_t)M_ * 4);
  __bf16* wqkvT = (__bf16*)alloc((size_t)2304 * 768 * 2);
  __bf16* woT = (__bf16*)alloc((size_t)768 * 768 * 2);
  __bf16* w1T = (__bf16*)alloc((size_t)3072 * 768 * 2);
  __bf16* w2T = (__bf16*)alloc((size_t)768 * 3072 * 2);
  __bf16* wpT = (__bf16*)alloc((size_t)512 * 768 * 2);
  float* bqkv = (float*)alloc((size_t)2304 * 4);

  // V-chunk sizing: cap the chunk so {embn, embT, Ec} working set (~34 MB at 65
  // tiles) stays L3-resident; buffers rotate so Ec never round-trips HBM.
  const size_t used = (size_t)(p - (char*)d_ws);
  const size_t avail = (ws_size > used + 4096) ? (ws_size - used - 4096) : 0;
  const size_t perTile = ((size_t)128 * 512 * 2) * 2 + (size_t)1024 * 128 * 2;
  size_t tp = avail / perTile;
  if (tp < 1) tp = 1;
  if (tp > 65) tp = 65;  // L3-residency cap (was 386: 199 MB fetch on GEMM1)
  const int tilesPer = (int)tp;
  const int nChunks = (386 + tilesPer - 1) / tilesPer;
  const int maxCols = tilesPer * 128;
  __bf16* embnC = (__bf16*)alloc((size_t)maxCols * 512 * 2);
  __bf16* embTC = (__bf16*)alloc((size_t)512 * maxCols * 2);
  __bf16* Ec = (__bf16*)alloc((size_t)1024 * maxCols * 2);

  hipMemsetAsync(rs, 0, M_ * 4, stream);
  hipMemsetAsync(kwacc, 0, (size_t)M_ * 512 * 4, stream);
  hipMemsetAsync(srcsum, 0, (size_t)M_ * 768 * 4, stream);

  // weight prep
  transpose_bf16k<<<dim3(24, 24), 256, 0, stream>>>(wq, wqkvT, 768, 768);
  transpose_bf16k<<<dim3(24, 24), 256, 0, stream>>>(wk, wqkvT + (size_t)768 * 768, 768, 768);
  transpose_bf16k<<<dim3(24, 24), 256, 0, stream>>>(wv, wqkvT + (size_t)2 * 768 * 768, 768, 768);
  transpose_bf16k<<<dim3(24, 24), 256, 0, stream>>>(wo, woT, 768, 768);
  transpose_bf16k<<<dim3(96, 24), 256, 0, stream>>>(w1, w1T, 768, 3072);
  transpose_bf16k<<<dim3(24, 96), 256, 0, stream>>>(w2, w2T, 3072, 768);
  transpose_bf16k<<<dim3(16, 24), 256, 0, stream>>>(wp, wpT, 768, 512);
  concat_bias_k<<<9, 256, 0, stream>>>(bq, bk, bv, bqkv);

  // pooling + transformer
  seg_partial_k<<<dim3(16, 16), 256, 0, stream>>>(audio, align, alen, srcsum);
  pool_fin_k<<<M_, 256, 0, stream>>>(srcsum, align, alen, anum, ln1g, ln1b, srcf, srcb);
  gemm_nt<0><<<dim3(8, 18, 1), 256, 0, stream>>>(srcb, wqkvT, bqkv, qkv, nullptr, 2304, 768, 24);
  attn_k<<<128, 256, 0, stream>>>(qkv, anum, ctxb);
  gemm_nt<0><<<dim3(8, 6, 1), 256, 0, stream>>>(ctxb, woT, bo, ybuf, nullptr, 768, 768, 24);
  add_ln_k<<<M_, 256, 0, stream>>>(ybuf, srcf, lnag, lnab, xf, xb);
  gemm_nt<1><<<dim3(8, 24, 1), 256, 0, stream>>>(xb, w1T, b1, hb, nullptr, 3072, 768, 24);
  gemm_nt<0><<<dim3(8, 6, 1), 256, 0, stream>>>(hb, w2T, b2, ybuf, nullptr, 768, 3072, 96);
  add_ln_k<<<M_, 256, 0, stream>>>(ybuf, xf, lnbg, lnbb, nullptr, x2b);
  gemm_nt<0><<<dim3(8, 4, 1), 256, 0, stream>>>(x2b, wpT, bp, kw, nullptr, 512, 768, 24);
  l2norm_bf16_k<<<M_, 256, 0, stream>>>(kw, kwn);

  // vocab loop: embprep (norm+transpose), GEMM1 exp+rowsum, GEMM2 split-K.
  // Chunks are L3-resident; kwacc/rs accumulate across chunks via atomics.
  for (int c = 0; c < nChunks; ++c) {
    const int t0 = c * tilesPer;
    const int nt = min(tilesPer, 386 - t0);
    const int v0 = t0 * 128, nc = nt * 128;
    embprep_k<<<nc / 32, 256, 0, stream>>>(emb + (size_t)v0 * 512, embnC, embTC, nc);
    gemm_nt<2><<<dim3(8, nt, 1), 256, 0, stream>>>(kwn, embnC, nullptr, Ec, rs, nc, 512, 16);
    const int totIt = nc >> 5;
    const int kpz = (totIt + 7) / 8;
    gemm_nt<3><<<dim3(8, 4, 8), 256, 0, stream>>>(Ec, embTC, nullptr, kwacc, nullptr, 512, nc, kpz);
  }
  final_scale_k<<<M_, 256, 0, stream>>>(kwacc, rs, out);
}

// Round 4
// 910.831 us; speedup vs baseline: 1.0250x; 1.0250x over previous
//
#include <hip/hip_runtime.h>
#include <hip/hip_bf16.h>
#include <math.h>

#define B_  16
#define T_  1024
#define D_  768
#define S_  64
#define H_  8
#define DH_ 96
#define FF_ 3072
#define TD_ 512
#define V_  49408
#define M_  1024  // B_*S_
#define ZSLICES 8

typedef __bf16 bf16_8 __attribute__((ext_vector_type(8)));
typedef __bf16 bf16x4 __attribute__((ext_vector_type(4)));
typedef float f32x4 __attribute__((ext_vector_type(4)));

__device__ __forceinline__ void async16(const void* g, void* lds) {
  __builtin_amdgcn_global_load_lds((const __attribute__((address_space(1))) void*)g,
                                   (__attribute__((address_space(3))) void*)lds,
                                   16, 0, 0);
}

__device__ __forceinline__ float blk_sum256(float v, float* red) {
#pragma unroll
  for (int o = 32; o > 0; o >>= 1) v += __shfl_down(v, o, 64);
  const int w = threadIdx.x >> 6;
  if ((threadIdx.x & 63) == 0) red[w] = v;
  __syncthreads();
  float t = red[0] + red[1] + red[2] + red[3];
  __syncthreads();
  return t;
}

// ---------------- GEMM: C[M,N] = A[M,K](bf16) * B[N,K]^T(bf16), fp32 acc ----------
// MODE 0: fp32 out (+bias)  1: relu bf16 out (+bias)  2: exp bf16 out + fused rowsum
// MODE 4: plain fp32 write to per-z slice   5: read-add-write to per-z slice
template <int MODE>
__global__ __launch_bounds__(256, 2) void gemm_nt(
    const __bf16* __restrict__ A, const __bf16* __restrict__ Bm,
    const float* __restrict__ bias, void* __restrict__ Cv,
    float* __restrict__ rsum, int Nr, int Kr, int kIterPerZ) {
  __shared__ __bf16 Als[128 * 32];
  __shared__ __bf16 Bls[128 * 32];
  const int tid = threadIdx.x;
  const int w = tid >> 6, l = tid & 63;
  const int m0 = blockIdx.x * 128, n0 = blockIdx.y * 128;
  const int totIt = Kr >> 5;
  const int it0 = blockIdx.z * kIterPerZ;
  const int nIt = min(kIterPerZ, totIt - it0);
  if (nIt <= 0) return;

  const int i0 = w * 128 + l, i1 = i0 + 64;
  const int ra0 = i0 >> 2, ca0 = ((i0 & 3) ^ ((i0 >> 3) & 3)) * 8;
  const int ra1 = i1 >> 2, ca1 = ((i1 & 3) ^ ((i1 >> 3) & 3)) * 8;
  const __bf16* gA0 = A + (size_t)(m0 + ra0) * Kr + ca0;
  const __bf16* gA1 = A + (size_t)(m0 + ra1) * Kr + ca1;
  const __bf16* gB0 = Bm + (size_t)(n0 + ra0) * Kr + ca0;
  const __bf16* gB1 = Bm + (size_t)(n0 + ra1) * Kr + ca1;
  __bf16* lA0 = &Als[(w * 128 + 0) * 8];
  __bf16* lA1 = &Als[(w * 128 + 64) * 8];
  __bf16* lB0 = &Bls[(w * 128 + 0) * 8];
  __bf16* lB1 = &Bls[(w * 128 + 64) * 8];

  const int wm = (w & 1) * 64, wn = (w >> 1) * 64;
  const int frow = l & 15, fq = l >> 4;
  const int fc = (fq ^ ((frow >> 1) & 3)) * 8;

  f32x4 acc[4][4];
  const f32x4 zero = {0.f, 0.f, 0.f, 0.f};
#pragma unroll
  for (int a = 0; a < 4; ++a)
#pragma unroll
    for (int b = 0; b < 4; ++b) acc[a][b] = zero;

  for (int it = 0; it < nIt; ++it) {
    const size_t k0 = (size_t)(it0 + it) << 5;
    __syncthreads();
    async16(gA0 + k0, lA0);
    async16(gA1 + k0, lA1);
    async16(gB0 + k0, lB0);
    async16(gB1 + k0, lB1);
    __syncthreads();
    bf16_8 af[4], bf[4];
#pragma unroll
    for (int mi = 0; mi < 4; ++mi)
      af[mi] = *(const bf16_8*)&Als[(wm + mi * 16 + frow) * 32 + fc];
#pragma unroll
    for (int ni = 0; ni < 4; ++ni)
      bf[ni] = *(const bf16_8*)&Bls[(wn + ni * 16 + frow) * 32 + fc];
#pragma unroll
    for (int mi = 0; mi < 4; ++mi)
#pragma unroll
      for (int ni = 0; ni < 4; ++ni)
        acc[mi][ni] = __builtin_amdgcn_mfma_f32_16x16x32_bf16(af[mi], bf[ni], acc[mi][ni], 0, 0, 0);
  }

  if (MODE == 2) {
#pragma unroll
    for (int mi = 0; mi < 4; ++mi) {
#pragma unroll
      for (int r = 0; r < 4; ++r) {
        const int row = m0 + wm + mi * 16 + fq * 4 + r;
        float partial = 0.f;
#pragma unroll
        for (int ni = 0; ni < 4; ++ni) {
          const int col = n0 + wn + ni * 16 + frow;
          const __bf16 h = (__bf16)exp2f(acc[mi][ni][r] * 1.4426950408889634f);
          ((__bf16*)Cv)[(size_t)row * Nr + col] = h;
          partial += (float)h;
        }
#pragma unroll
        for (int off = 1; off < 16; off <<= 1) partial += __shfl_xor(partial, off, 64);
        if (frow == 0) atomicAdd(&rsum[row], partial);
      }
    }
    return;
  }

  float* Cs = (float*)Cv;
  if (MODE == 4 || MODE == 5) Cs += (size_t)blockIdx.z * M_ * TD_;

#pragma unroll
  for (int mi = 0; mi < 4; ++mi) {
#pragma unroll
    for (int r = 0; r < 4; ++r) {
      const int row = m0 + wm + mi * 16 + fq * 4 + r;
#pragma unroll
      for (int ni = 0; ni < 4; ++ni) {
        const int col = n0 + wn + ni * 16 + frow;
        float v = acc[mi][ni][r];
        if (MODE == 0) {
          if (bias) v += bias[col];
          Cs[(size_t)row * Nr + col] = v;
        } else if (MODE == 1) {
          v += bias[col];
          ((__bf16*)Cv)[(size_t)row * Nr + col] = (__bf16)fmaxf(v, 0.f);
        } else if (MODE == 4) {
          Cs[(size_t)row * Nr + col] = v;
        } else {  // MODE 5: accumulate into this block's private slice tile
          Cs[(size_t)row * Nr + col] += v;
        }
      }
    }
  }
}

// -------- transpose fp32 [R][C] -> bf16 [C][R] (weights) --------------------------
__global__ __launch_bounds__(256) void transpose_bf16k(const float* __restrict__ src,
                                                       __bf16* __restrict__ dst, int R, int C) {
  __shared__ float tl[32][33];
  const int tx = threadIdx.x & 31, ty = threadIdx.x >> 5;
  const int c0 = blockIdx.x * 32, r0 = blockIdx.y * 32;
#pragma unroll
  for (int k = 0; k < 4; ++k) {
    int r = ty + k * 8;
    tl[r][tx] = src[(size_t)(r0 + r) * C + (c0 + tx)];
  }
  __syncthreads();
#pragma unroll
  for (int k = 0; k < 4; ++k) {
    int r = ty + k * 8;
    dst[(size_t)(c0 + r) * R + (r0 + tx)] = (__bf16)tl[tx][r];
  }
}

__global__ __launch_bounds__(256) void concat_bias_k(const float* __restrict__ bq,
                                                     const float* __restrict__ bk,
                                                     const float* __restrict__ bv,
                                                     float* __restrict__ dst) {
  int i = blockIdx.x * 256 + threadIdx.x;
  if (i < 768) dst[i] = bq[i];
  else if (i < 1536) dst[i] = bk[i - 768];
  else if (i < 2304) dst[i] = bv[i - 1536];
}

// -------- emb prep: read fp32 emb once, write normalized bf16 + raw transpose -----
__global__ __launch_bounds__(256) void embprep_k(const float* __restrict__ emb,
                                                 __bf16* __restrict__ embn,
                                                 __bf16* __restrict__ embT, int nc) {
  __shared__ __bf16 tile[32][516];
  const int tid = threadIdx.x;
  const int r = tid >> 4, i = tid & 15;
  const int vloc = blockIdx.x * 32;
  float4 f[2][8];
  float ss[2] = {0.f, 0.f};
#pragma unroll
  for (int h = 0; h < 2; ++h) {
    const int v = vloc + r + h * 16;
    const float4* row = (const float4*)(emb + (size_t)v * 512);
#pragma unroll
    for (int j = 0; j < 8; ++j) {
      float4 x = row[i + j * 16];
      f[h][j] = x;
      ss[h] += x.x * x.x + x.y * x.y + x.z * x.z + x.w * x.w;
    }
  }
#pragma unroll
  for (int off = 1; off < 16; off <<= 1) {
    ss[0] += __shfl_xor(ss[0], off, 64);
    ss[1] += __shfl_xor(ss[1], off, 64);
  }
  float inv[2];
#pragma unroll
  for (int h = 0; h < 2; ++h) inv[h] = 1.f / fmaxf(sqrtf(ss[h]), 1e-8f);
#pragma unroll
  for (int h = 0; h < 2; ++h) {
    const int vr = r + h * 16;
#pragma unroll
    for (int j = 0; j < 8; ++j) {
      const int d4 = i + j * 16;
      float4 x = f[h][j];
      tile[vr][d4 * 4 + 0] = (__bf16)x.x;
      tile[vr][d4 * 4 + 1] = (__bf16)x.y;
      tile[vr][d4 * 4 + 2] = (__bf16)x.z;
      tile[vr][d4 * 4 + 3] = (__bf16)x.w;
      bf16x4 o;
      o[0] = (__bf16)(x.x * inv[h]);
      o[1] = (__bf16)(x.y * inv[h]);
      o[2] = (__bf16)(x.z * inv[h]);
      o[3] = (__bf16)(x.w * inv[h]);
      *(bf16x4*)(embn + (size_t)(vloc + vr) * 512 + d4 * 4) = o;
    }
  }
  __syncthreads();
#pragma unroll
  for (int c = 0; c < 2; ++c) {
    const int d = tid + c * 256;
    uint us[16];
#pragma unroll
    for (int v = 0; v < 32; v += 2) {
      __bf16 a = tile[v][d], b = tile[v + 1][d];
      us[v >> 1] = (uint)(*(unsigned short*)&a) | ((uint)(*(unsigned short*)&b) << 16);
    }
    uint4* dst = (uint4*)(embT + (size_t)d * nc + vloc);
#pragma unroll
    for (int q = 0; q < 4; ++q) {
      uint4 u = {us[q * 4], us[q * 4 + 1], us[q * 4 + 2], us[q * 4 + 3]};
      dst[q] = u;
    }
  }
}

// -------- segment pooling phase 1: chunked streaming partial sums (atomics) -------
__global__ __launch_bounds__(256) void seg_partial_k(
    const float* __restrict__ af, const int* __restrict__ align,
    const int* __restrict__ alen, float* __restrict__ srcsum) {
  __shared__ int ts_s[64], te_s[64], segid[64];
  const int b = blockIdx.x, ch = blockIdx.y;
  const int tid = threadIdx.x;
  if (tid < 64) {
    const int ts = align[(b * 64 + tid) * 2];
    const int te = align[(b * 64 + tid) * 2 + 1];
    const int teff = (te == alen[b]) ? T_ : te;
    ts_s[tid] = min(max(ts, 0), T_);
    te_s[tid] = min(max(teff, 0), T_);
  }
  __syncthreads();
  const int t0 = ch * 64;
  if (tid < 64) {
    const int t = t0 + tid;
    int s = -1;
    if (ts_s[0] <= t) {
      int lo = 0, hi = 63;
      while (lo < hi) {
        const int mid = (lo + hi + 1) >> 1;
        if (ts_s[mid] <= t) lo = mid; else hi = mid - 1;
      }
      s = (t < te_s[lo]) ? lo : -1;
    }
    segid[tid] = s;
  }
  __syncthreads();
  float a0 = 0.f, a1 = 0.f, a2 = 0.f;
  int cur = -1;
  for (int k = 0; k < 64; ++k) {
    const int s = segid[k];
    if (s != cur) {
      if (cur >= 0) {
        float* dst = srcsum + (size_t)(b * 64 + cur) * 768 + tid;
        atomicAdd(dst, a0); atomicAdd(dst + 256, a1); atomicAdd(dst + 512, a2);
      }
      a0 = a1 = a2 = 0.f;
      cur = s;
    }
    if (s >= 0) {
      const float* row = af + ((size_t)b * T_ + t0 + k) * 768 + tid;
      a0 += row[0]; a1 += row[256]; a2 += row[512];
    }
  }
  if (cur >= 0) {
    float* dst = srcsum + (size_t)(b * 64 + cur) * 768 + tid;
    atomicAdd(dst, a0); atomicAdd(dst + 256, a1); atomicAdd(dst + 512, a2);
  }
}

// -------- segment pooling phase 2: mean + mask + LayerNorm ------------------------
__global__ __launch_bounds__(256) void pool_fin_k(
    const float* __restrict__ srcsum, const int* __restrict__ align,
    const int* __restrict__ alen, const int* __restrict__ anum,
    const float* __restrict__ g, const float* __restrict__ be,
    float* __restrict__ srcf, __bf16* __restrict__ srcb) {
  __shared__ float red[4];
  const int m = blockIdx.x, b = m >> 6, s = m & 63;
  const int tid = threadIdx.x;
  const int ts = align[m * 2], te = align[m * 2 + 1];
  const bool valid = (ts >= 0) && (s < anum[b]);
  const int teff = (te == alen[b]) ? T_ : te;
  const int tsc = min(max(ts, 0), T_), tec = min(max(teff, 0), T_);
  const float invc = 1.f / (float)max(tec - tsc, 1);
  float x[3];
#pragma unroll
  for (int u = 0; u < 3; ++u) {
    const int d = tid + u * 256;
    x[u] = valid ? srcsum[(size_t)m * 768 + d] * invc : 0.f;
  }
  const float mean = blk_sum256(x[0] + x[1] + x[2], red) * (1.f / 768.f);
  float lv = 0.f;
#pragma unroll
  for (int u = 0; u < 3; ++u) { float dd = x[u] - mean; lv += dd * dd; }
  const float var = blk_sum256(lv, red) * (1.f / 768.f);
  const float rstd = rsqrtf(var + 1e-5f);
#pragma unroll
  for (int u = 0; u < 3; ++u) {
    const int d = tid + u * 256;
    const float o = (x[u] - mean) * rstd * g[d] + be[d];
    srcf[(size_t)m * 768 + d] = o;
    srcb[(size_t)m * 768 + d] = (__bf16)o;
  }
}

// -------- residual add + LayerNorm ------------------------------------------------
__global__ __launch_bounds__(256) void add_ln_k(
    const float* __restrict__ a, const float* __restrict__ r,
    const float* __restrict__ g, const float* __restrict__ be,
    float* __restrict__ outf, __bf16* __restrict__ outb) {
  __shared__ float red[4];
  const int m = blockIdx.x, tid = threadIdx.x;
  float x[3];
#pragma unroll
  for (int u = 0; u < 3; ++u) {
    const size_t idx = (size_t)m * 768 + tid + u * 256;
    x[u] = a[idx] + (r ? r[idx] : 0.f);
  }
  const float mean = blk_sum256(x[0] + x[1] + x[2], red) * (1.f / 768.f);
  float lv = 0.f;
#pragma unroll
  for (int u = 0; u < 3; ++u) { float dd = x[u] - mean; lv += dd * dd; }
  const float var = blk_sum256(lv, red) * (1.f / 768.f);
  const float rstd = rsqrtf(var + 1e-5f);
#pragma unroll
  for (int u = 0; u < 3; ++u) {
    const int d = tid + u * 256;
    const float o = (x[u] - mean) * rstd * g[d] + be[d];
    if (outf) outf[(size_t)m * 768 + d] = o;
    if (outb) outb[(size_t)m * 768 + d] = (__bf16)o;
  }
}

// -------- attention: one block per (b,h) ------------------------------------------
__global__ __launch_bounds__(256) void attn_k(const float* __restrict__ qkv,
                                              const int* __restrict__ anum,
                                              __bf16* __restrict__ ctx) {
  __shared__ __bf16 qb[64 * 96], kb[64 * 96], vb[64 * 96];
  __shared__ float sc[64 * 66];
  const int tid = threadIdx.x;
  const int b = blockIdx.x >> 3, h = blockIdx.x & 7;
  const int colq = h * 96;
  for (int idx = tid; idx < 6144; idx += 256) {
    const int s = idx / 96, d = idx - s * 96;
    const size_t base = ((size_t)(b * 64 + s)) * 2304 + colq + d;
    qb[idx] = (__bf16)qkv[base];
    kb[idx] = (__bf16)qkv[base + 768];
    vb[idx] = (__bf16)qkv[base + 1536];
  }
  __syncthreads();
  const int i = tid >> 2, jg = tid & 3;
  for (int jj = 0; jj < 16; ++jj) {
    const int j = jg * 16 + jj;
    float dot = 0.f;
    for (int d = 0; d < 96; ++d) dot += (float)qb[i * 96 + d] * (float)kb[j * 96 + d];
    sc[i * 66 + j] = dot * 0.10206207261596577f;  // 1/sqrt(96)
  }
  __syncthreads();
  if (tid < 64) {
    const int an = anum[b];
    float mx = -3.4e38f;
    for (int j = 0; j < 64; ++j) {
      float v = (j < an) ? sc[tid * 66 + j] : -1e30f;
      sc[tid * 66 + j] = v;
      mx = fmaxf(mx, v);
    }
    float sum = 0.f;
    for (int j = 0; j < 64; ++j) {
      float e = exp2f((sc[tid * 66 + j] - mx) * 1.4426950408889634f);
      sc[tid * 66 + j] = e;
      sum += e;
    }
    const float inv = 1.f / sum;
    for (int j = 0; j < 64; ++j) sc[tid * 66 + j] *= inv;
  }
  __syncthreads();
  const int dg = tid & 3;
  for (int dd = 0; dd < 24; ++dd) {
    const int d = dg * 24 + dd;
    float s2 = 0.f;
    for (int j = 0; j < 64; ++j) s2 += sc[i * 66 + j] * (float)vb[j * 96 + d];
    ctx[((size_t)(b * 64 + i)) * 768 + colq + d] = (__bf16)s2;
  }
}

// -------- row L2-normalize (512-wide) fp32 -> bf16 (for kw) -----------------------
__global__ __launch_bounds__(256) void l2norm_bf16_k(const float* __restrict__ src,
                                                     __bf16* __restrict__ dst) {
  __shared__ float red[4];
  const int rix = blockIdx.x, tid = threadIdx.x;
  const float* row = src + (size_t)rix * 512;
  const float v0 = row[tid], v1 = row[tid + 256];
  const float tot = blk_sum256(v0 * v0 + v1 * v1, red);
  const float inv = 1.f / fmaxf(sqrtf(tot), 1e-8f);
  dst[(size_t)rix * 512 + tid] = (__bf16)(v0 * inv);
  dst[(size_t)rix * 512 + tid + 256] = (__bf16)(v1 * inv);
}

// -------- final: sum split-K slices, scale by 1/rowsum ----------------------------
__global__ __launch_bounds__(256) void final_reduce_k(const float* __restrict__ slices,
                                                      const float* __restrict__ rs,
                                                      float* __restrict__ out) {
  const int m = blockIdx.x, d = threadIdx.x;
  const float inv = 1.f / rs[m];
  float s0 = 0.f, s1 = 0.f;
#pragma unroll
  for (int z = 0; z < ZSLICES; ++z) {
    const float* sl = slices + (size_t)z * M_ * TD_ + (size_t)m * TD_;
    s0 += sl[d];
    s1 += sl[d + 256];
  }
  out[(size_t)m * TD_ + d] = s0 * inv;
  out[(size_t)m * TD_ + d + 256] = s1 * inv;
}

extern "C" void kernel_launch(void* const* d_in, const int* in_sizes, int n_in,
                              void* d_out, int out_size, void* d_ws, size_t ws_size,
                              hipStream_t stream) {
  const float* audio = (const float*)d_in[0];
  const float* ln1g = (const float*)d_in[1];
  const float* ln1b = (const float*)d_in[2];
  const float* wq = (const float*)d_in[3];
  const float* bq = (const float*)d_in[4];
  const float* wk = (const float*)d_in[5];
  const float* bk = (const float*)d_in[6];
  const float* wv = (const float*)d_in[7];
  const float* bv = (const float*)d_in[8];
  const float* wo = (const float*)d_in[9];
  const float* bo = (const float*)d_in[10];
  const float* lnag = (const float*)d_in[11];
  const float* lnab = (const float*)d_in[12];
  const float* w1 = (const float*)d_in[13];
  const float* b1 = (const float*)d_in[14];
  const float* w2 = (const float*)d_in[15];
  const float* b2 = (const float*)d_in[16];
  const float* lnbg = (const float*)d_in[17];
  const float* lnbb = (const float*)d_in[18];
  const float* wp = (const float*)d_in[19];
  const float* bp = (const float*)d_in[20];
  const float* emb = (const float*)d_in[21];
  const int* alen = (const int*)d_in[22];
  const int* align = (const int*)d_in[23];
  const int* anum = (const int*)d_in[24];
  float* out = (float*)d_out;

  char* p = (char*)d_ws;
  auto alloc = [&](size_t bytes) {
    char* r = p;
    p += (bytes + 255) & ~(size_t)255;
    return r;
  };
  float* srcsum = (float*)alloc((size_t)M_ * 768 * 4);
  float* srcf = (float*)alloc((size_t)M_ * 768 * 4);
  __bf16* srcb = (__bf16*)alloc((size_t)M_ * 768 * 2);
  float* qkv = (float*)alloc((size_t)M_ * 2304 * 4);
  __bf16* ctxb = (__bf16*)alloc((size_t)M_ * 768 * 2);
  float* ybuf = (float*)alloc((size_t)M_ * 768 * 4);
  float* xf = (float*)alloc((size_t)M_ * 768 * 4);
  __bf16* xb = (__bf16*)alloc((size_t)M_ * 768 * 2);
  __bf16* hb = (__bf16*)alloc((size_t)M_ * FF_ * 2);
  __bf16* x2b = (__bf16*)alloc((size_t)M_ * 768 * 2);
  float* kw = (float*)alloc((size_t)M_ * 512 * 4);
  __bf16* kwn = (__bf16*)alloc((size_t)M_ * 512 * 2);
  float* kwslice = (float*)alloc((size_t)ZSLICES * M_ * 512 * 4);  // 16 MB split-K slices
  float* rs = (float*)alloc((size_t)M_ * 4);
  __bf16* wqkvT = (__bf16*)alloc((size_t)2304 * 768 * 2);
  __bf16* woT = (__bf16*)alloc((size_t)768 * 768 * 2);
  __bf16* w1T = (__bf16*)alloc((size_t)3072 * 768 * 2);
  __bf16* w2T = (__bf16*)alloc((size_t)768 * 3072 * 2);
  __bf16* wpT = (__bf16*)alloc((size_t)512 * 768 * 2);
  float* bqkv = (float*)alloc((size_t)2304 * 4);

  // V-chunk sizing: cap so {embn, embT, Ec} (~34 MB at 65 tiles) stays L3-resident.
  const size_t used = (size_t)(p - (char*)d_ws);
  const size_t avail = (ws_size > used + 4096) ? (ws_size - used - 4096) : 0;
  const size_t perTile = ((size_t)128 * 512 * 2) * 2 + (size_t)1024 * 128 * 2;
  size_t tp = avail / perTile;
  if (tp < 1) tp = 1;
  if (tp > 65) tp = 65;
  const int tilesPer = (int)tp;
  const int nChunks = (386 + tilesPer - 1) / tilesPer;
  const int maxCols = tilesPer * 128;
  __bf16* embnC = (__bf16*)alloc((size_t)maxCols * 512 * 2);
  __bf16* embTC = (__bf16*)alloc((size_t)512 * maxCols * 2);
  __bf16* Ec = (__bf16*)alloc((size_t)1024 * maxCols * 2);

  hipMemsetAsync(rs, 0, M_ * 4, stream);
  hipMemsetAsync(srcsum, 0, (size_t)M_ * 768 * 4, stream);

  // weight prep
  transpose_bf16k<<<dim3(24, 24), 256, 0, stream>>>(wq, wqkvT, 768, 768);
  transpose_bf16k<<<dim3(24, 24), 256, 0, stream>>>(wk, wqkvT + (size_t)768 * 768, 768, 768);
  transpose_bf16k<<<dim3(24, 24), 256, 0, stream>>>(wv, wqkvT + (size_t)2 * 768 * 768, 768, 768);
  transpose_bf16k<<<dim3(24, 24), 256, 0, stream>>>(wo, woT, 768, 768);
  transpose_bf16k<<<dim3(96, 24), 256, 0, stream>>>(w1, w1T, 768, 3072);
  transpose_bf16k<<<dim3(24, 96), 256, 0, stream>>>(w2, w2T, 3072, 768);
  transpose_bf16k<<<dim3(16, 24), 256, 0, stream>>>(wp, wpT, 768, 512);
  concat_bias_k<<<9, 256, 0, stream>>>(bq, bk, bv, bqkv);

  // pooling + transformer
  seg_partial_k<<<dim3(16, 16), 256, 0, stream>>>(audio, align, alen, srcsum);
  pool_fin_k<<<M_, 256, 0, stream>>>(srcsum, align, alen, anum, ln1g, ln1b, srcf, srcb);
  gemm_nt<0><<<dim3(8, 18, 1), 256, 0, stream>>>(srcb, wqkvT, bqkv, qkv, nullptr, 2304, 768, 24);
  attn_k<<<128, 256, 0, stream>>>(qkv, anum, ctxb);
  gemm_nt<0><<<dim3(8, 6, 1), 256, 0, stream>>>(ctxb, woT, bo, ybuf, nullptr, 768, 768, 24);
  add_ln_k<<<M_, 256, 0, stream>>>(ybuf, srcf, lnag, lnab, xf, xb);
  gemm_nt<1><<<dim3(8, 24, 1), 256, 0, stream>>>(xb, w1T, b1, hb, nullptr, 3072, 768, 24);
  gemm_nt<0><<<dim3(8, 6, 1), 256, 0, stream>>>(hb, w2T, b2, ybuf, nullptr, 768, 3072, 96);
  add_ln_k<<<M_, 256, 0, stream>>>(ybuf, xf, lnbg, lnbb, nullptr, x2b);
  gemm_nt<0><<<dim3(8, 4, 1), 256, 0, stream>>>(x2b, wpT, bp, kw, nullptr, 512, 768, 24);
  l2norm_bf16_k<<<M_, 256, 0, stream>>>(kw, kwn);

  // vocab loop: embprep, GEMM1 exp+rowsum, GEMM2 split-K into private slices
  // (block (x,y,z) owns its 128x128 tile of slice z: chunk 0 writes, rest rmw-add —
  //  no atomics, no contention; chunks serialized by stream order)
  for (int c = 0; c < nChunks; ++c) {
    const int t0 = c * tilesPer;
    const int nt = min(tilesPer, 386 - t0);
    const int v0 = t0 * 128, nc = nt * 128;
    embprep_k<<<nc / 32, 256, 0, stream>>>(emb + (size_t)v0 * 512, embnC, embTC, nc);
    gemm_nt<2><<<dim3(8, nt, 1), 256, 0, stream>>>(kwn, embnC, nullptr, Ec, rs, nc, 512, 16);
    const int totIt = nc >> 5;
    const int kpz = (totIt + ZSLICES - 1) / ZSLICES;
    if (c == 0)
      gemm_nt<4><<<dim3(8, 4, ZSLICES), 256, 0, stream>>>(Ec, embTC, nullptr, kwslice, nullptr, 512, nc, kpz);
    else
      gemm_nt<5><<<dim3(8, 4, ZSLICES), 256, 0, stream>>>(Ec, embTC, nullptr, kwslice, nullptr, 512, nc, kpz);
  }
  final_reduce_k<<<M_, 256, 0, stream>>>(kwslice, rs, out);
}

// Round 5
// 739.237 us; speedup vs baseline: 1.2630x; 1.2321x over previous
//
#include <hip/hip_runtime.h>
#include <hip/hip_bf16.h>
#include <math.h>

#define B_  16
#define T_  1024
#define D_  768
#define S_  64
#define H_  8
#define DH_ 96
#define FF_ 3072
#define TD_ 512
#define V_  49408
#define M_  1024  // B_*S_
#define ZSL 16

typedef __bf16 bf16_8 __attribute__((ext_vector_type(8)));
typedef __bf16 bf16x4 __attribute__((ext_vector_type(4)));
typedef float f32x4 __attribute__((ext_vector_type(4)));

__device__ __forceinline__ void async16(const void* g, void* lds) {
  __builtin_amdgcn_global_load_lds((const __attribute__((address_space(1))) void*)g,
                                   (__attribute__((address_space(3))) void*)lds,
                                   16, 0, 0);
}

__device__ __forceinline__ float blk_sum256(float v, float* red) {
#pragma unroll
  for (int o = 32; o > 0; o >>= 1) v += __shfl_down(v, o, 64);
  const int w = threadIdx.x >> 6;
  if ((threadIdx.x & 63) == 0) red[w] = v;
  __syncthreads();
  float t = red[0] + red[1] + red[2] + red[3];
  __syncthreads();
  return t;
}

// ---------------- GEMM: C[M,N] = A[M,K](bf16) * B[N,K]^T(bf16), fp32 acc ----------
// MODE 0: fp32 out (+bias)        1: relu bf16 out (+bias)
// MODE 2: exp bf16 out (LDS-coalesced) + fused rowsum
// MODE 4: fp32 write to private z-slice (LDS-coalesced)
// MODE 5: fp32 read-add-write to private z-slice (fallback path only)
template <int MODE>
__global__ __launch_bounds__(256, 2) void gemm_nt(
    const __bf16* __restrict__ A, const __bf16* __restrict__ Bm,
    const float* __restrict__ bias, void* __restrict__ Cv,
    float* __restrict__ rsum, int Nr, int Kr, int kIterPerZ) {
  constexpr int SMEMB = (MODE == 2) ? (128 * 136 * 2) : ((MODE == 4) ? (32 * 140 * 4) : 16384);
  __shared__ __align__(16) char smem_raw[SMEMB];
  __bf16* Als = (__bf16*)smem_raw;
  __bf16* Bls = (__bf16*)(smem_raw + 8192);

  const int tid = threadIdx.x;
  const int w = tid >> 6, l = tid & 63;
  const int m0 = blockIdx.x * 128, n0 = blockIdx.y * 128;
  const int totIt = Kr >> 5;
  const int it0 = blockIdx.z * kIterPerZ;
  const int nIt = min(kIterPerZ, totIt - it0);
  if (nIt <= 0) return;

  const int i0 = w * 128 + l, i1 = i0 + 64;
  const int ra0 = i0 >> 2, ca0 = ((i0 & 3) ^ ((i0 >> 3) & 3)) * 8;
  const int ra1 = i1 >> 2, ca1 = ((i1 & 3) ^ ((i1 >> 3) & 3)) * 8;
  const __bf16* gA0 = A + (size_t)(m0 + ra0) * Kr + ca0;
  const __bf16* gA1 = A + (size_t)(m0 + ra1) * Kr + ca1;
  const __bf16* gB0 = Bm + (size_t)(n0 + ra0) * Kr + ca0;
  const __bf16* gB1 = Bm + (size_t)(n0 + ra1) * Kr + ca1;
  __bf16* lA0 = &Als[(w * 128 + 0) * 8];
  __bf16* lA1 = &Als[(w * 128 + 64) * 8];
  __bf16* lB0 = &Bls[(w * 128 + 0) * 8];
  __bf16* lB1 = &Bls[(w * 128 + 64) * 8];

  const int wm = (w & 1) * 64, wn = (w >> 1) * 64;
  const int frow = l & 15, fq = l >> 4;
  const int fc = (fq ^ ((frow >> 1) & 3)) * 8;

  f32x4 acc[4][4];
  const f32x4 zero = {0.f, 0.f, 0.f, 0.f};
#pragma unroll
  for (int a = 0; a < 4; ++a)
#pragma unroll
    for (int b = 0; b < 4; ++b) acc[a][b] = zero;

  for (int it = 0; it < nIt; ++it) {
    const size_t k0 = (size_t)(it0 + it) << 5;
    __syncthreads();
    async16(gA0 + k0, lA0);
    async16(gA1 + k0, lA1);
    async16(gB0 + k0, lB0);
    async16(gB1 + k0, lB1);
    __syncthreads();
    bf16_8 af[4], bf[4];
#pragma unroll
    for (int mi = 0; mi < 4; ++mi)
      af[mi] = *(const bf16_8*)&Als[(wm + mi * 16 + frow) * 32 + fc];
#pragma unroll
    for (int ni = 0; ni < 4; ++ni)
      bf[ni] = *(const bf16_8*)&Bls[(wn + ni * 16 + frow) * 32 + fc];
#pragma unroll
    for (int mi = 0; mi < 4; ++mi)
#pragma unroll
      for (int ni = 0; ni < 4; ++ni)
        acc[mi][ni] = __builtin_amdgcn_mfma_f32_16x16x32_bf16(af[mi], bf[ni], acc[mi][ni], 0, 0, 0);
  }

  if (MODE == 2) {
    // exp epilogue: stage bf16 tile in LDS, coalesced 16B writes; fused rowsum
    __syncthreads();
    __bf16* Cst = (__bf16*)smem_raw;  // [128][136]
#pragma unroll
    for (int mi = 0; mi < 4; ++mi) {
#pragma unroll
      for (int r = 0; r < 4; ++r) {
        const int rowl = wm + mi * 16 + fq * 4 + r;
        float partial = 0.f;
#pragma unroll
        for (int ni = 0; ni < 4; ++ni) {
          const int coll = wn + ni * 16 + frow;
          const __bf16 h = (__bf16)exp2f(acc[mi][ni][r] * 1.4426950408889634f);
          Cst[rowl * 136 + coll] = h;
          partial += (float)h;
        }
#pragma unroll
        for (int off = 1; off < 16; off <<= 1) partial += __shfl_xor(partial, off, 64);
        if (frow == 0) atomicAdd(&rsum[m0 + rowl], partial);
      }
    }
    __syncthreads();
#pragma unroll
    for (int p2 = 0; p2 < 8; ++p2) {
      const int cidx = p2 * 256 + tid;  // 0..2047: 128 rows x 16 chunks of 16B
      const int rowl = cidx >> 4, cp = cidx & 15;
      uint4 u = *(const uint4*)&Cst[rowl * 136 + cp * 8];
      *(uint4*)&((__bf16*)Cv)[(size_t)(m0 + rowl) * Nr + n0 + cp * 8] = u;
    }
    return;
  }

  if (MODE == 4) {
    // private-slice write: LDS-stage fp32, 4 passes of 32 rows, coalesced 16B writes
    float* Cs = (float*)Cv + (size_t)blockIdx.z * M_ * TD_;
    float* Fst = (float*)smem_raw;  // [32][140]
#pragma unroll
    for (int pass = 0; pass < 4; ++pass) {
      __syncthreads();
#pragma unroll
      for (int mi = 0; mi < 4; ++mi) {
        if (((wm + mi * 16) >> 5) == pass) {
#pragma unroll
          for (int r = 0; r < 4; ++r) {
            const int rl = (wm + mi * 16 + fq * 4 + r) & 31;
#pragma unroll
            for (int ni = 0; ni < 4; ++ni)
              Fst[rl * 140 + wn + ni * 16 + frow] = acc[mi][ni][r];
          }
        }
      }
      __syncthreads();
#pragma unroll
      for (int q = 0; q < 4; ++q) {
        const int c = q * 256 + tid;  // 0..1023: 32 rows x 32 float4
        const int rowl = c >> 5, cp = c & 31;
        float4 v4 = *(const float4*)&Fst[rowl * 140 + cp * 4];
        *(float4*)&Cs[(size_t)(m0 + pass * 32 + rowl) * Nr + n0 + cp * 4] = v4;
      }
    }
    return;
  }

  float* Cs = (float*)Cv;
  if (MODE == 5) Cs += (size_t)blockIdx.z * M_ * TD_;
#pragma unroll
  for (int mi = 0; mi < 4; ++mi) {
#pragma unroll
    for (int r = 0; r < 4; ++r) {
      const int row = m0 + wm + mi * 16 + fq * 4 + r;
#pragma unroll
      for (int ni = 0; ni < 4; ++ni) {
        const int col = n0 + wn + ni * 16 + frow;
        float v = acc[mi][ni][r];
        if (MODE == 0) {
          if (bias) v += bias[col];
          Cs[(size_t)row * Nr + col] = v;
        } else if (MODE == 1) {
          v += bias[col];
          ((__bf16*)Cv)[(size_t)row * Nr + col] = (__bf16)fmaxf(v, 0.f);
        } else {  // MODE 5
          Cs[(size_t)row * Nr + col] += v;
        }
      }
    }
  }
}

// -------- transpose fp32 [R][C] -> bf16 [C][R] (weights) --------------------------
__global__ __launch_bounds__(256) void transpose_bf16k(const float* __restrict__ src,
                                                       __bf16* __restrict__ dst, int R, int C) {
  __shared__ float tl[32][33];
  const int tx = threadIdx.x & 31, ty = threadIdx.x >> 5;
  const int c0 = blockIdx.x * 32, r0 = blockIdx.y * 32;
#pragma unroll
  for (int k = 0; k < 4; ++k) {
    int r = ty + k * 8;
    tl[r][tx] = src[(size_t)(r0 + r) * C + (c0 + tx)];
  }
  __syncthreads();
#pragma unroll
  for (int k = 0; k < 4; ++k) {
    int r = ty + k * 8;
    dst[(size_t)(c0 + r) * R + (r0 + tx)] = (__bf16)tl[tx][r];
  }
}

__global__ __launch_bounds__(256) void concat_bias_k(const float* __restrict__ bq,
                                                     const float* __restrict__ bk,
                                                     const float* __restrict__ bv,
                                                     float* __restrict__ dst) {
  int i = blockIdx.x * 256 + threadIdx.x;
  if (i < 768) dst[i] = bq[i];
  else if (i < 1536) dst[i] = bk[i - 768];
  else if (i < 2304) dst[i] = bv[i - 1536];
}

// -------- emb prep: read fp32 emb once, write normalized bf16 + raw transpose -----
__global__ __launch_bounds__(256) void embprep_k(const float* __restrict__ emb,
                                                 __bf16* __restrict__ embn,
                                                 __bf16* __restrict__ embT, int nc) {
  __shared__ __bf16 tile[32][516];
  const int tid = threadIdx.x;
  const int r = tid >> 4, i = tid & 15;
  const int vloc = blockIdx.x * 32;
  float4 f[2][8];
  float ss[2] = {0.f, 0.f};
#pragma unroll
  for (int h = 0; h < 2; ++h) {
    const int v = vloc + r + h * 16;
    const float4* row = (const float4*)(emb + (size_t)v * 512);
#pragma unroll
    for (int j = 0; j < 8; ++j) {
      float4 x = row[i + j * 16];
      f[h][j] = x;
      ss[h] += x.x * x.x + x.y * x.y + x.z * x.z + x.w * x.w;
    }
  }
#pragma unroll
  for (int off = 1; off < 16; off <<= 1) {
    ss[0] += __shfl_xor(ss[0], off, 64);
    ss[1] += __shfl_xor(ss[1], off, 64);
  }
  float inv[2];
#pragma unroll
  for (int h = 0; h < 2; ++h) inv[h] = 1.f / fmaxf(sqrtf(ss[h]), 1e-8f);
#pragma unroll
  for (int h = 0; h < 2; ++h) {
    const int vr = r + h * 16;
#pragma unroll
    for (int j = 0; j < 8; ++j) {
      const int d4 = i + j * 16;
      float4 x = f[h][j];
      tile[vr][d4 * 4 + 0] = (__bf16)x.x;
      tile[vr][d4 * 4 + 1] = (__bf16)x.y;
      tile[vr][d4 * 4 + 2] = (__bf16)x.z;
      tile[vr][d4 * 4 + 3] = (__bf16)x.w;
      bf16x4 o;
      o[0] = (__bf16)(x.x * inv[h]);
      o[1] = (__bf16)(x.y * inv[h]);
      o[2] = (__bf16)(x.z * inv[h]);
      o[3] = (__bf16)(x.w * inv[h]);
      *(bf16x4*)(embn + (size_t)(vloc + vr) * 512 + d4 * 4) = o;
    }
  }
  __syncthreads();
#pragma unroll
  for (int c = 0; c < 2; ++c) {
    const int d = tid + c * 256;
    uint us[16];
#pragma unroll
    for (int v = 0; v < 32; v += 2) {
      __bf16 a = tile[v][d], b = tile[v + 1][d];
      us[v >> 1] = (uint)(*(unsigned short*)&a) | ((uint)(*(unsigned short*)&b) << 16);
    }
    uint4* dst = (uint4*)(embT + (size_t)d * nc + vloc);
#pragma unroll
    for (int q = 0; q < 4; ++q) {
      uint4 u = {us[q * 4], us[q * 4 + 1], us[q * 4 + 2], us[q * 4 + 3]};
      dst[q] = u;
    }
  }
}

// -------- segment pooling phase 1: chunked streaming partial sums (atomics) -------
__global__ __launch_bounds__(256) void seg_partial_k(
    const float* __restrict__ af, const int* __restrict__ align,
    const int* __restrict__ alen, float* __restrict__ srcsum) {
  __shared__ int ts_s[64], te_s[64], segid[64];
  const int b = blockIdx.x, ch = blockIdx.y;
  const int tid = threadIdx.x;
  if (tid < 64) {
    const int ts = align[(b * 64 + tid) * 2];
    const int te = align[(b * 64 + tid) * 2 + 1];
    const int teff = (te == alen[b]) ? T_ : te;
    ts_s[tid] = min(max(ts, 0), T_);
    te_s[tid] = min(max(teff, 0), T_);
  }
  __syncthreads();
  const int t0 = ch * 64;
  if (tid < 64) {
    const int t = t0 + tid;
    int s = -1;
    if (ts_s[0] <= t) {
      int lo = 0, hi = 63;
      while (lo < hi) {
        const int mid = (lo + hi + 1) >> 1;
        if (ts_s[mid] <= t) lo = mid; else hi = mid - 1;
      }
      s = (t < te_s[lo]) ? lo : -1;
    }
    segid[tid] = s;
  }
  __syncthreads();
  float a0 = 0.f, a1 = 0.f, a2 = 0.f;
  int cur = -1;
  for (int k = 0; k < 64; ++k) {
    const int s = segid[k];
    if (s != cur) {
      if (cur >= 0) {
        float* dst = srcsum + (size_t)(b * 64 + cur) * 768 + tid;
        atomicAdd(dst, a0); atomicAdd(dst + 256, a1); atomicAdd(dst + 512, a2);
      }
      a0 = a1 = a2 = 0.f;
      cur = s;
    }
    if (s >= 0) {
      const float* row = af + ((size_t)b * T_ + t0 + k) * 768 + tid;
      a0 += row[0]; a1 += row[256]; a2 += row[512];
    }
  }
  if (cur >= 0) {
    float* dst = srcsum + (size_t)(b * 64 + cur) * 768 + tid;
    atomicAdd(dst, a0); atomicAdd(dst + 256, a1); atomicAdd(dst + 512, a2);
  }
}

// -------- segment pooling phase 2: mean + mask + LayerNorm ------------------------
__global__ __launch_bounds__(256) void pool_fin_k(
    const float* __restrict__ srcsum, const int* __restrict__ align,
    const int* __restrict__ alen, const int* __restrict__ anum,
    const float* __restrict__ g, const float* __restrict__ be,
    float* __restrict__ srcf, __bf16* __restrict__ srcb) {
  __shared__ float red[4];
  const int m = blockIdx.x, b = m >> 6, s = m & 63;
  const int tid = threadIdx.x;
  const int ts = align[m * 2], te = align[m * 2 + 1];
  const bool valid = (ts >= 0) && (s < anum[b]);
  const int teff = (te == alen[b]) ? T_ : te;
  const int tsc = min(max(ts, 0), T_), tec = min(max(teff, 0), T_);
  const float invc = 1.f / (float)max(tec - tsc, 1);
  float x[3];
#pragma unroll
  for (int u = 0; u < 3; ++u) {
    const int d = tid + u * 256;
    x[u] = valid ? srcsum[(size_t)m * 768 + d] * invc : 0.f;
  }
  const float mean = blk_sum256(x[0] + x[1] + x[2], red) * (1.f / 768.f);
  float lv = 0.f;
#pragma unroll
  for (int u = 0; u < 3; ++u) { float dd = x[u] - mean; lv += dd * dd; }
  const float var = blk_sum256(lv, red) * (1.f / 768.f);
  const float rstd = rsqrtf(var + 1e-5f);
#pragma unroll
  for (int u = 0; u < 3; ++u) {
    const int d = tid + u * 256;
    const float o = (x[u] - mean) * rstd * g[d] + be[d];
    srcf[(size_t)m * 768 + d] = o;
    srcb[(size_t)m * 768 + d] = (__bf16)o;
  }
}

// -------- residual add + LayerNorm ------------------------------------------------
__global__ __launch_bounds__(256) void add_ln_k(
    const float* __restrict__ a, const float* __restrict__ r,
    const float* __restrict__ g, const float* __restrict__ be,
    float* __restrict__ outf, __bf16* __restrict__ outb) {
  __shared__ float red[4];
  const int m = blockIdx.x, tid = threadIdx.x;
  float x[3];
#pragma unroll
  for (int u = 0; u < 3; ++u) {
    const size_t idx = (size_t)m * 768 + tid + u * 256;
    x[u] = a[idx] + (r ? r[idx] : 0.f);
  }
  const float mean = blk_sum256(x[0] + x[1] + x[2], red) * (1.f / 768.f);
  float lv = 0.f;
#pragma unroll
  for (int u = 0; u < 3; ++u) { float dd = x[u] - mean; lv += dd * dd; }
  const float var = blk_sum256(lv, red) * (1.f / 768.f);
  const float rstd = rsqrtf(var + 1e-5f);
#pragma unroll
  for (int u = 0; u < 3; ++u) {
    const int d = tid + u * 256;
    const float o = (x[u] - mean) * rstd * g[d] + be[d];
    if (outf) outf[(size_t)m * 768 + d] = o;
    if (outb) outb[(size_t)m * 768 + d] = (__bf16)o;
  }
}

// -------- attention: one block per (b,h) ------------------------------------------
__global__ __launch_bounds__(256) void attn_k(const float* __restrict__ qkv,
                                              const int* __restrict__ anum,
                                              __bf16* __restrict__ ctx) {
  __shared__ __bf16 qb[64 * 96], kb[64 * 96], vb[64 * 96];
  __shared__ float sc[64 * 66];
  const int tid = threadIdx.x;
  const int b = blockIdx.x >> 3, h = blockIdx.x & 7;
  const int colq = h * 96;
  for (int idx = tid; idx < 6144; idx += 256) {
    const int s = idx / 96, d = idx - s * 96;
    const size_t base = ((size_t)(b * 64 + s)) * 2304 + colq + d;
    qb[idx] = (__bf16)qkv[base];
    kb[idx] = (__bf16)qkv[base + 768];
    vb[idx] = (__bf16)qkv[base + 1536];
  }
  __syncthreads();
  const int i = tid >> 2, jg = tid & 3;
  for (int jj = 0; jj < 16; ++jj) {
    const int j = jg * 16 + jj;
    float dot = 0.f;
    for (int d = 0; d < 96; ++d) dot += (float)qb[i * 96 + d] * (float)kb[j * 96 + d];
    sc[i * 66 + j] = dot * 0.10206207261596577f;  // 1/sqrt(96)
  }
  __syncthreads();
  if (tid < 64) {
    const int an = anum[b];
    float mx = -3.4e38f;
    for (int j = 0; j < 64; ++j) {
      float v = (j < an) ? sc[tid * 66 + j] : -1e30f;
      sc[tid * 66 + j] = v;
      mx = fmaxf(mx, v);
    }
    float sum = 0.f;
    for (int j = 0; j < 64; ++j) {
      float e = exp2f((sc[tid * 66 + j] - mx) * 1.4426950408889634f);
      sc[tid * 66 + j] = e;
      sum += e;
    }
    const float inv = 1.f / sum;
    for (int j = 0; j < 64; ++j) sc[tid * 66 + j] *= inv;
  }
  __syncthreads();
  const int dg = tid & 3;
  for (int dd = 0; dd < 24; ++dd) {
    const int d = dg * 24 + dd;
    float s2 = 0.f;
    for (int j = 0; j < 64; ++j) s2 += sc[i * 66 + j] * (float)vb[j * 96 + d];
    ctx[((size_t)(b * 64 + i)) * 768 + colq + d] = (__bf16)s2;
  }
}

// -------- row L2-normalize (512-wide) fp32 -> bf16 (for kw) -----------------------
__global__ __launch_bounds__(256) void l2norm_bf16_k(const float* __restrict__ src,
                                                     __bf16* __restrict__ dst) {
  __shared__ float red[4];
  const int rix = blockIdx.x, tid = threadIdx.x;
  const float* row = src + (size_t)rix * 512;
  const float v0 = row[tid], v1 = row[tid + 256];
  const float tot = blk_sum256(v0 * v0 + v1 * v1, red);
  const float inv = 1.f / fmaxf(sqrtf(tot), 1e-8f);
  dst[(size_t)rix * 512 + tid] = (__bf16)(v0 * inv);
  dst[(size_t)rix * 512 + tid + 256] = (__bf16)(v1 * inv);
}

// -------- final: sum split-K slices, scale by 1/rowsum ----------------------------
__global__ __launch_bounds__(256) void final_reduce_k(const float* __restrict__ slices,
                                                      const float* __restrict__ rs,
                                                      float* __restrict__ out) {
  const int m = blockIdx.x, d = threadIdx.x;
  const float inv = 1.f / rs[m];
  float s0 = 0.f, s1 = 0.f;
#pragma unroll
  for (int z = 0; z < ZSL; ++z) {
    const float* sl = slices + (size_t)z * M_ * TD_ + (size_t)m * TD_;
    s0 += sl[d];
    s1 += sl[d + 256];
  }
  out[(size_t)m * TD_ + d] = s0 * inv;
  out[(size_t)m * TD_ + d + 256] = s1 * inv;
}

extern "C" void kernel_launch(void* const* d_in, const int* in_sizes, int n_in,
                              void* d_out, int out_size, void* d_ws, size_t ws_size,
                              hipStream_t stream) {
  const float* audio = (const float*)d_in[0];
  const float* ln1g = (const float*)d_in[1];
  const float* ln1b = (const float*)d_in[2];
  const float* wq = (const float*)d_in[3];
  const float* bq = (const float*)d_in[4];
  const float* wk = (const float*)d_in[5];
  const float* bk = (const float*)d_in[6];
  const float* wv = (const float*)d_in[7];
  const float* bv = (const float*)d_in[8];
  const float* wo = (const float*)d_in[9];
  const float* bo = (const float*)d_in[10];
  const float* lnag = (const float*)d_in[11];
  const float* lnab = (const float*)d_in[12];
  const float* w1 = (const float*)d_in[13];
  const float* b1 = (const float*)d_in[14];
  const float* w2 = (const float*)d_in[15];
  const float* b2 = (const float*)d_in[16];
  const float* lnbg = (const float*)d_in[17];
  const float* lnbb = (const float*)d_in[18];
  const float* wp = (const float*)d_in[19];
  const float* bp = (const float*)d_in[20];
  const float* emb = (const float*)d_in[21];
  const int* alen = (const int*)d_in[22];
  const int* align = (const int*)d_in[23];
  const int* anum = (const int*)d_in[24];
  float* out = (float*)d_out;

  char* p = (char*)d_ws;
  auto alloc = [&](size_t bytes) {
    char* r = p;
    p += (bytes + 255) & ~(size_t)255;
    return r;
  };
  // --- overlay region: transformer temporaries (dead by vocab stage) double as
  //     kwslice (ZSL x M x TD fp32 = 33.6 MB; region below sums to 36.7 MB) ---
  float* kwslice = (float*)d_ws;
  float* srcsum = (float*)alloc((size_t)M_ * 768 * 4);
  float* srcf = (float*)alloc((size_t)M_ * 768 * 4);
  __bf16* srcb = (__bf16*)alloc((size_t)M_ * 768 * 2);
  float* qkv = (float*)alloc((size_t)M_ * 2304 * 4);
  __bf16* ctxb = (__bf16*)alloc((size_t)M_ * 768 * 2);
  float* ybuf = (float*)alloc((size_t)M_ * 768 * 4);
  float* xf = (float*)alloc((size_t)M_ * 768 * 4);
  __bf16* xb = (__bf16*)alloc((size_t)M_ * 768 * 2);
  __bf16* hb = (__bf16*)alloc((size_t)M_ * FF_ * 2);
  __bf16* x2b = (__bf16*)alloc((size_t)M_ * 768 * 2);
  float* kw = (float*)alloc((size_t)M_ * 512 * 4);
  {  // pad overlay region to >= kwslice size
    const size_t need = (size_t)ZSL * M_ * TD_ * 4;
    const size_t cur = (size_t)(p - (char*)d_ws);
    if (cur < need) alloc(need - cur);
  }
  // --- persistent-through-vocab allocations ---
  __bf16* kwn = (__bf16*)alloc((size_t)M_ * 512 * 2);
  float* rs = (float*)alloc((size_t)M_ * 4);
  __bf16* wqkvT = (__bf16*)alloc((size_t)2304 * 768 * 2);
  __bf16* woT = (__bf16*)alloc((size_t)768 * 768 * 2);
  __bf16* w1T = (__bf16*)alloc((size_t)3072 * 768 * 2);
  __bf16* w2T = (__bf16*)alloc((size_t)768 * 3072 * 2);
  __bf16* wpT = (__bf16*)alloc((size_t)512 * 768 * 2);
  float* bqkv = (float*)alloc((size_t)2304 * 4);

  const size_t used = (size_t)(p - (char*)d_ws);
  const size_t avail = (ws_size > used + 4096) ? (ws_size - used - 4096) : 0;
  const size_t perTile = ((size_t)128 * 512 * 2) * 2 + (size_t)1024 * 128 * 2;
  size_t tp = avail / perTile;
  if (tp < 1) tp = 1;
  if (tp > 386) tp = 386;
  const int tilesPer = (int)tp;
  const int nChunks = (386 + tilesPer - 1) / tilesPer;
  const int maxCols = tilesPer * 128;
  __bf16* embnC = (__bf16*)alloc((size_t)maxCols * 512 * 2);
  __bf16* embTC = (__bf16*)alloc((size_t)512 * maxCols * 2);
  __bf16* Ec = (__bf16*)alloc((size_t)1024 * maxCols * 2);

  hipMemsetAsync(rs, 0, M_ * 4, stream);
  hipMemsetAsync(srcsum, 0, (size_t)M_ * 768 * 4, stream);

  // weight prep
  transpose_bf16k<<<dim3(24, 24), 256, 0, stream>>>(wq, wqkvT, 768, 768);
  transpose_bf16k<<<dim3(24, 24), 256, 0, stream>>>(wk, wqkvT + (size_t)768 * 768, 768, 768);
  transpose_bf16k<<<dim3(24, 24), 256, 0, stream>>>(wv, wqkvT + (size_t)2 * 768 * 768, 768, 768);
  transpose_bf16k<<<dim3(24, 24), 256, 0, stream>>>(wo, woT, 768, 768);
  transpose_bf16k<<<dim3(96, 24), 256, 0, stream>>>(w1, w1T, 768, 3072);
  transpose_bf16k<<<dim3(24, 96), 256, 0, stream>>>(w2, w2T, 3072, 768);
  transpose_bf16k<<<dim3(16, 24), 256, 0, stream>>>(wp, wpT, 768, 512);
  concat_bias_k<<<9, 256, 0, stream>>>(bq, bk, bv, bqkv);

  // pooling + transformer
  seg_partial_k<<<dim3(16, 16), 256, 0, stream>>>(audio, align, alen, srcsum);
  pool_fin_k<<<M_, 256, 0, stream>>>(srcsum, align, alen, anum, ln1g, ln1b, srcf, srcb);
  gemm_nt<0><<<dim3(8, 18, 1), 256, 0, stream>>>(srcb, wqkvT, bqkv, qkv, nullptr, 2304, 768, 24);
  attn_k<<<128, 256, 0, stream>>>(qkv, anum, ctxb);
  gemm_nt<0><<<dim3(8, 6, 1), 256, 0, stream>>>(ctxb, woT, bo, ybuf, nullptr, 768, 768, 24);
  add_ln_k<<<M_, 256, 0, stream>>>(ybuf, srcf, lnag, lnab, xf, xb);
  gemm_nt<1><<<dim3(8, 24, 1), 256, 0, stream>>>(xb, w1T, b1, hb, nullptr, 3072, 768, 24);
  gemm_nt<0><<<dim3(8, 6, 1), 256, 0, stream>>>(hb, w2T, b2, ybuf, nullptr, 768, 3072, 96);
  add_ln_k<<<M_, 256, 0, stream>>>(ybuf, xf, lnbg, lnbb, nullptr, x2b);
  gemm_nt<0><<<dim3(8, 4, 1), 256, 0, stream>>>(x2b, wpT, bp, kw, nullptr, 512, 768, 24);
  l2norm_bf16_k<<<M_, 256, 0, stream>>>(kw, kwn);

  // vocab stage (after this point the overlay region is dead -> kwslice is live)
  if (nChunks == 1) {
    // monolithic: one embprep, one GEMM1 (8x386), one GEMM2 (8,4,16; 512 blocks)
    embprep_k<<<V_ / 32, 256, 0, stream>>>(emb, embnC, embTC, V_);
    gemm_nt<2><<<dim3(8, 386, 1), 256, 0, stream>>>(kwn, embnC, nullptr, Ec, rs, V_, 512, 16);
    const int kpz = (V_ / 32 + ZSL - 1) / ZSL;  // 1544/16 -> 97
    gemm_nt<4><<<dim3(8, 4, ZSL), 256, 0, stream>>>(Ec, embTC, nullptr, kwslice, nullptr, 512, V_, kpz);
  } else {
    for (int c = 0; c < nChunks; ++c) {
      const int t0 = c * tilesPer;
      const int nt = min(tilesPer, 386 - t0);
      const int v0 = t0 * 128, nc = nt * 128;
      embprep_k<<<nc / 32, 256, 0, stream>>>(emb + (size_t)v0 * 512, embnC, embTC, nc);
      gemm_nt<2><<<dim3(8, nt, 1), 256, 0, stream>>>(kwn, embnC, nullptr, Ec, rs, nc, 512, 16);
      const int totIt = nc >> 5;
      const int kpz = (totIt + ZSL - 1) / ZSL;
      if (c == 0)
        gemm_nt<4><<<dim3(8, 4, ZSL), 256, 0, stream>>>(Ec, embTC, nullptr, kwslice, nullptr, 512, nc, kpz);
      else
        gemm_nt<5><<<dim3(8, 4, ZSL), 256, 0, stream>>>(Ec, embTC, nullptr, kwslice, nullptr, 512, nc, kpz);
    }
  }
  final_reduce_k<<<M_, 256, 0, stream>>>(kwslice, rs, out);
}

// Round 6
// 722.169 us; speedup vs baseline: 1.2928x; 1.0236x over previous
//
#include <hip/hip_runtime.h>
#include <hip/hip_bf16.h>
#include <math.h>

#define B_  16
#define T_  1024
#define D_  768
#define S_  64
#define H_  8
#define DH_ 96
#define FF_ 3072
#define TD_ 512
#define V_  49408
#define M_  1024  // B_*S_
#define ZSL 16

typedef __bf16 bf16_8 __attribute__((ext_vector_type(8)));
typedef __bf16 bf16x4 __attribute__((ext_vector_type(4)));
typedef float f32x4 __attribute__((ext_vector_type(4)));

__device__ __forceinline__ void async16(const void* g, void* lds) {
  __builtin_amdgcn_global_load_lds((const __attribute__((address_space(1))) void*)g,
                                   (__attribute__((address_space(3))) void*)lds,
                                   16, 0, 0);
}

__device__ __forceinline__ float blk_sum256(float v, float* red) {
#pragma unroll
  for (int o = 32; o > 0; o >>= 1) v += __shfl_down(v, o, 64);
  const int w = threadIdx.x >> 6;
  if ((threadIdx.x & 63) == 0) red[w] = v;
  __syncthreads();
  float t = red[0] + red[1] + red[2] + red[3];
  __syncthreads();
  return t;
}

// ---------------- GEMM 128x128: C[M,N] = A[M,K](bf16) * B[N,K]^T(bf16) ------------
// MODE 0: fp32 out (+bias)  1: relu bf16 out (+bias)
// MODE 4: fp32 write to private z-slice     5: read-add-write to private z-slice
// SWZ=1: grid must be (8,4,ZSL); decode (m,n,z) so all 8 m-blocks of one (n,z)
//        land on one XCD (id%8 == const) -> B-slice fetched once per XCD L2.
template <int MODE, int SWZ>
__global__ __launch_bounds__(256, 2) void gemm_nt(
    const __bf16* __restrict__ A, const __bf16* __restrict__ Bm,
    const float* __restrict__ bias, void* __restrict__ Cv,
    int Nr, int Kr, int kIterPerZ) {
  __shared__ __bf16 Als[128 * 32];
  __shared__ __bf16 Bls[128 * 32];
  const int tid = threadIdx.x;
  const int w = tid >> 6, l = tid & 63;
  int mb, nb, zb;
  if (SWZ) {
    const int f = blockIdx.x + 8 * blockIdx.y + 32 * blockIdx.z;  // [0,512)
    const int q = f >> 6, k = f & 7;
    mb = (f >> 3) & 7;
    const int nz = q * 8 + k;  // (n,z) pinned to XCD k
    nb = nz & 3;
    zb = nz >> 2;
  } else {
    mb = blockIdx.x; nb = blockIdx.y; zb = blockIdx.z;
  }
  const int m0 = mb * 128, n0 = nb * 128;
  const int totIt = Kr >> 5;
  const int it0 = zb * kIterPerZ;
  const int nIt = min(kIterPerZ, totIt - it0);
  if (nIt <= 0) return;

  const int i0 = w * 128 + l, i1 = i0 + 64;
  const int ra0 = i0 >> 2, ca0 = ((i0 & 3) ^ ((i0 >> 3) & 3)) * 8;
  const int ra1 = i1 >> 2, ca1 = ((i1 & 3) ^ ((i1 >> 3) & 3)) * 8;
  const __bf16* gA0 = A + (size_t)(m0 + ra0) * Kr + ca0;
  const __bf16* gA1 = A + (size_t)(m0 + ra1) * Kr + ca1;
  const __bf16* gB0 = Bm + (size_t)(n0 + ra0) * Kr + ca0;
  const __bf16* gB1 = Bm + (size_t)(n0 + ra1) * Kr + ca1;
  __bf16* lA0 = &Als[(w * 128 + 0) * 8];
  __bf16* lA1 = &Als[(w * 128 + 64) * 8];
  __bf16* lB0 = &Bls[(w * 128 + 0) * 8];
  __bf16* lB1 = &Bls[(w * 128 + 64) * 8];

  const int wm = (w & 1) * 64, wn = (w >> 1) * 64;
  const int frow = l & 15, fq = l >> 4;
  const int fc = (fq ^ ((frow >> 1) & 3)) * 8;

  f32x4 acc[4][4];
  const f32x4 zero = {0.f, 0.f, 0.f, 0.f};
#pragma unroll
  for (int a = 0; a < 4; ++a)
#pragma unroll
    for (int b = 0; b < 4; ++b) acc[a][b] = zero;

  for (int it = 0; it < nIt; ++it) {
    const size_t k0 = (size_t)(it0 + it) << 5;
    __syncthreads();
    async16(gA0 + k0, lA0);
    async16(gA1 + k0, lA1);
    async16(gB0 + k0, lB0);
    async16(gB1 + k0, lB1);
    __syncthreads();
    bf16_8 af[4], bf[4];
#pragma unroll
    for (int mi = 0; mi < 4; ++mi)
      af[mi] = *(const bf16_8*)&Als[(wm + mi * 16 + frow) * 32 + fc];
#pragma unroll
    for (int ni = 0; ni < 4; ++ni)
      bf[ni] = *(const bf16_8*)&Bls[(wn + ni * 16 + frow) * 32 + fc];
#pragma unroll
    for (int mi = 0; mi < 4; ++mi)
#pragma unroll
      for (int ni = 0; ni < 4; ++ni)
        acc[mi][ni] = __builtin_amdgcn_mfma_f32_16x16x32_bf16(af[mi], bf[ni], acc[mi][ni], 0, 0, 0);
  }

  float* Cs = (float*)Cv;
  if (MODE == 4 || MODE == 5) Cs += (size_t)zb * M_ * TD_;
#pragma unroll
  for (int mi = 0; mi < 4; ++mi) {
#pragma unroll
    for (int r = 0; r < 4; ++r) {
      const int row = m0 + wm + mi * 16 + fq * 4 + r;
#pragma unroll
      for (int ni = 0; ni < 4; ++ni) {
        const int col = n0 + wn + ni * 16 + frow;
        float v = acc[mi][ni][r];
        if (MODE == 0) {
          if (bias) v += bias[col];
          Cs[(size_t)row * Nr + col] = v;
        } else if (MODE == 1) {
          v += bias[col];
          ((__bf16*)Cv)[(size_t)row * Nr + col] = (__bf16)fmaxf(v, 0.f);
        } else if (MODE == 4) {
          Cs[(size_t)row * Nr + col] = v;
        } else {
          Cs[(size_t)row * Nr + col] += v;
        }
      }
    }
  }
}

// ---------------- GEMM 256x128 (GEMM1): exp epilogue + fused rowsum ---------------
// grid: 1-D, 4*nTiles blocks, XCD-swizzled: the 4 m-blocks of n-tile n have
// id%8 == n%8 and are adjacent on that XCD -> B-tile fetched once per XCD.
__global__ __launch_bounds__(256, 2) void gemm_big_exp(
    const __bf16* __restrict__ A, const __bf16* __restrict__ Bm,
    __bf16* __restrict__ C, float* __restrict__ rsum,
    int Nr, int Kr, int nTiles) {
  __shared__ __bf16 Als[256 * 32];  // 16 KB
  __shared__ __bf16 Bls[128 * 32];  // 8 KB
  const int tid = threadIdx.x;
  const int w = tid >> 6, l = tid & 63;
  const int f = blockIdx.x;
  int mb, nb;
  const int nT8 = (nTiles >> 3) << 3;
  if (f < 4 * nT8) {
    const int q = f >> 5, rem = f & 31;
    mb = rem >> 3;
    nb = q * 8 + (rem & 7);
  } else {
    const int r = f - 4 * nT8, tl = nTiles - nT8;
    mb = r / tl;
    nb = nT8 + r % tl;
  }
  const int m0 = mb * 256, n0 = nb * 128;
  const int nIt = Kr >> 5;

  // staging: A = 1024 16B-chunks (4 per wave-group), B = 512 (2 per wave-group)
  int raA[4], caA[4], raB[2], caB[2];
  __bf16 *ldA[4], *ldB[2];
#pragma unroll
  for (int g = 0; g < 4; ++g) {
    const int i = g * 256 + w * 64 + l;
    raA[g] = i >> 2;
    caA[g] = ((i & 3) ^ ((i >> 3) & 3)) * 8;
    ldA[g] = &Als[(g * 256 + w * 64) * 8];
  }
#pragma unroll
  for (int g = 0; g < 2; ++g) {
    const int i = g * 256 + w * 64 + l;
    raB[g] = i >> 2;
    caB[g] = ((i & 3) ^ ((i >> 3) & 3)) * 8;
    ldB[g] = &Bls[(g * 256 + w * 64) * 8];
  }

  const int frow = l & 15, fq = l >> 4;
  const int fc = (fq ^ ((frow >> 1) & 3)) * 8;

  f32x4 acc[4][8];
  const f32x4 zero = {0.f, 0.f, 0.f, 0.f};
#pragma unroll
  for (int a = 0; a < 4; ++a)
#pragma unroll
    for (int b = 0; b < 8; ++b) acc[a][b] = zero;

  for (int it = 0; it < nIt; ++it) {
    const size_t k0 = (size_t)it << 5;
    __syncthreads();
#pragma unroll
    for (int g = 0; g < 4; ++g)
      async16(A + (size_t)(m0 + raA[g]) * Kr + caA[g] + k0, ldA[g]);
#pragma unroll
    for (int g = 0; g < 2; ++g)
      async16(Bm + (size_t)(n0 + raB[g]) * Kr + caB[g] + k0, ldB[g]);
    __syncthreads();
    bf16_8 af[4], bf[8];
#pragma unroll
    for (int mi = 0; mi < 4; ++mi)
      af[mi] = *(const bf16_8*)&Als[(w * 64 + mi * 16 + frow) * 32 + fc];
#pragma unroll
    for (int ni = 0; ni < 8; ++ni)
      bf[ni] = *(const bf16_8*)&Bls[(ni * 16 + frow) * 32 + fc];
#pragma unroll
    for (int mi = 0; mi < 4; ++mi)
#pragma unroll
      for (int ni = 0; ni < 8; ++ni)
        acc[mi][ni] = __builtin_amdgcn_mfma_f32_16x16x32_bf16(af[mi], bf[ni], acc[mi][ni], 0, 0, 0);
  }

#pragma unroll
  for (int mi = 0; mi < 4; ++mi) {
#pragma unroll
    for (int r = 0; r < 4; ++r) {
      const int row = m0 + w * 64 + mi * 16 + fq * 4 + r;
      float partial = 0.f;
#pragma unroll
      for (int ni = 0; ni < 8; ++ni) {
        const int col = n0 + ni * 16 + frow;
        const __bf16 h = (__bf16)exp2f(acc[mi][ni][r] * 1.4426950408889634f);
        C[(size_t)row * Nr + col] = h;
        partial += (float)h;
      }
#pragma unroll
      for (int off = 1; off < 16; off <<= 1) partial += __shfl_xor(partial, off, 64);
      if (frow == 0) atomicAdd(&rsum[row], partial);
    }
  }
}

// -------- transpose fp32 [R][C] -> bf16 [C][R] (weights) --------------------------
__global__ __launch_bounds__(256) void transpose_bf16k(const float* __restrict__ src,
                                                       __bf16* __restrict__ dst, int R, int C) {
  __shared__ float tl[32][33];
  const int tx = threadIdx.x & 31, ty = threadIdx.x >> 5;
  const int c0 = blockIdx.x * 32, r0 = blockIdx.y * 32;
#pragma unroll
  for (int k = 0; k < 4; ++k) {
    int r = ty + k * 8;
    tl[r][tx] = src[(size_t)(r0 + r) * C + (c0 + tx)];
  }
  __syncthreads();
#pragma unroll
  for (int k = 0; k < 4; ++k) {
    int r = ty + k * 8;
    dst[(size_t)(c0 + r) * R + (r0 + tx)] = (__bf16)tl[tx][r];
  }
}

__global__ __launch_bounds__(256) void concat_bias_k(const float* __restrict__ bq,
                                                     const float* __restrict__ bk,
                                                     const float* __restrict__ bv,
                                                     float* __restrict__ dst) {
  int i = blockIdx.x * 256 + threadIdx.x;
  if (i < 768) dst[i] = bq[i];
  else if (i < 1536) dst[i] = bk[i - 768];
  else if (i < 2304) dst[i] = bv[i - 1536];
}

// -------- emb prep: read fp32 emb once, write normalized bf16 + raw transpose -----
__global__ __launch_bounds__(256) void embprep_k(const float* __restrict__ emb,
                                                 __bf16* __restrict__ embn,
                                                 __bf16* __restrict__ embT, int nc) {
  __shared__ __bf16 tile[32][516];
  const int tid = threadIdx.x;
  const int r = tid >> 4, i = tid & 15;
  const int vloc = blockIdx.x * 32;
  float4 f[2][8];
  float ss[2] = {0.f, 0.f};
#pragma unroll
  for (int h = 0; h < 2; ++h) {
    const int v = vloc + r + h * 16;
    const float4* row = (const float4*)(emb + (size_t)v * 512);
#pragma unroll
    for (int j = 0; j < 8; ++j) {
      float4 x = row[i + j * 16];
      f[h][j] = x;
      ss[h] += x.x * x.x + x.y * x.y + x.z * x.z + x.w * x.w;
    }
  }
#pragma unroll
  for (int off = 1; off < 16; off <<= 1) {
    ss[0] += __shfl_xor(ss[0], off, 64);
    ss[1] += __shfl_xor(ss[1], off, 64);
  }
  float inv[2];
#pragma unroll
  for (int h = 0; h < 2; ++h) inv[h] = 1.f / fmaxf(sqrtf(ss[h]), 1e-8f);
#pragma unroll
  for (int h = 0; h < 2; ++h) {
    const int vr = r + h * 16;
#pragma unroll
    for (int j = 0; j < 8; ++j) {
      const int d4 = i + j * 16;
      float4 x = f[h][j];
      tile[vr][d4 * 4 + 0] = (__bf16)x.x;
      tile[vr][d4 * 4 + 1] = (__bf16)x.y;
      tile[vr][d4 * 4 + 2] = (__bf16)x.z;
      tile[vr][d4 * 4 + 3] = (__bf16)x.w;
      bf16x4 o;
      o[0] = (__bf16)(x.x * inv[h]);
      o[1] = (__bf16)(x.y * inv[h]);
      o[2] = (__bf16)(x.z * inv[h]);
      o[3] = (__bf16)(x.w * inv[h]);
      *(bf16x4*)(embn + (size_t)(vloc + vr) * 512 + d4 * 4) = o;
    }
  }
  __syncthreads();
#pragma unroll
  for (int c = 0; c < 2; ++c) {
    const int d = tid + c * 256;
    uint us[16];
#pragma unroll
    for (int v = 0; v < 32; v += 2) {
      __bf16 a = tile[v][d], b = tile[v + 1][d];
      us[v >> 1] = (uint)(*(unsigned short*)&a) | ((uint)(*(unsigned short*)&b) << 16);
    }
    uint4* dst = (uint4*)(embT + (size_t)d * nc + vloc);
#pragma unroll
    for (int q = 0; q < 4; ++q) {
      uint4 u = {us[q * 4], us[q * 4 + 1], us[q * 4 + 2], us[q * 4 + 3]};
      dst[q] = u;
    }
  }
}

// -------- segment pooling phase 1: chunked streaming partial sums (atomics) -------
__global__ __launch_bounds__(256) void seg_partial_k(
    const float* __restrict__ af, const int* __restrict__ align,
    const int* __restrict__ alen, float* __restrict__ srcsum) {
  __shared__ int ts_s[64], te_s[64], segid[64];
  const int b = blockIdx.x, ch = blockIdx.y;
  const int tid = threadIdx.x;
  if (tid < 64) {
    const int ts = align[(b * 64 + tid) * 2];
    const int te = align[(b * 64 + tid) * 2 + 1];
    const int teff = (te == alen[b]) ? T_ : te;
    ts_s[tid] = min(max(ts, 0), T_);
    te_s[tid] = min(max(teff, 0), T_);
  }
  __syncthreads();
  const int t0 = ch * 64;
  if (tid < 64) {
    const int t = t0 + tid;
    int s = -1;
    if (ts_s[0] <= t) {
      int lo = 0, hi = 63;
      while (lo < hi) {
        const int mid = (lo + hi + 1) >> 1;
        if (ts_s[mid] <= t) lo = mid; else hi = mid - 1;
      }
      s = (t < te_s[lo]) ? lo : -1;
    }
    segid[tid] = s;
  }
  __syncthreads();
  float a0 = 0.f, a1 = 0.f, a2 = 0.f;
  int cur = -1;
  for (int k = 0; k < 64; ++k) {
    const int s = segid[k];
    if (s != cur) {
      if (cur >= 0) {
        float* dst = srcsum + (size_t)(b * 64 + cur) * 768 + tid;
        atomicAdd(dst, a0); atomicAdd(dst + 256, a1); atomicAdd(dst + 512, a2);
      }
      a0 = a1 = a2 = 0.f;
      cur = s;
    }
    if (s >= 0) {
      const float* row = af + ((size_t)b * T_ + t0 + k) * 768 + tid;
      a0 += row[0]; a1 += row[256]; a2 += row[512];
    }
  }
  if (cur >= 0) {
    float* dst = srcsum + (size_t)(b * 64 + cur) * 768 + tid;
    atomicAdd(dst, a0); atomicAdd(dst + 256, a1); atomicAdd(dst + 512, a2);
  }
}

// -------- segment pooling phase 2: mean + mask + LayerNorm ------------------------
__global__ __launch_bounds__(256) void pool_fin_k(
    const float* __restrict__ srcsum, const int* __restrict__ align,
    const int* __restrict__ alen, const int* __restrict__ anum,
    const float* __restrict__ g, const float* __restrict__ be,
    float* __restrict__ srcf, __bf16* __restrict__ srcb) {
  __shared__ float red[4];
  const int m = blockIdx.x, b = m >> 6, s = m & 63;
  const int tid = threadIdx.x;
  const int ts = align[m * 2], te = align[m * 2 + 1];
  const bool valid = (ts >= 0) && (s < anum[b]);
  const int teff = (te == alen[b]) ? T_ : te;
  const int tsc = min(max(ts, 0), T_), tec = min(max(teff, 0), T_);
  const float invc = 1.f / (float)max(tec - tsc, 1);
  float x[3];
#pragma unroll
  for (int u = 0; u < 3; ++u) {
    const int d = tid + u * 256;
    x[u] = valid ? srcsum[(size_t)m * 768 + d] * invc : 0.f;
  }
  const float mean = blk_sum256(x[0] + x[1] + x[2], red) * (1.f / 768.f);
  float lv = 0.f;
#pragma unroll
  for (int u = 0; u < 3; ++u) { float dd = x[u] - mean; lv += dd * dd; }
  const float var = blk_sum256(lv, red) * (1.f / 768.f);
  const float rstd = rsqrtf(var + 1e-5f);
#pragma unroll
  for (int u = 0; u < 3; ++u) {
    const int d = tid + u * 256;
    const float o = (x[u] - mean) * rstd * g[d] + be[d];
    srcf[(size_t)m * 768 + d] = o;
    srcb[(size_t)m * 768 + d] = (__bf16)o;
  }
}

// -------- residual add + LayerNorm ------------------------------------------------
__global__ __launch_bounds__(256) void add_ln_k(
    const float* __restrict__ a, const float* __restrict__ r,
    const float* __restrict__ g, const float* __restrict__ be,
    float* __restrict__ outf, __bf16* __restrict__ outb) {
  __shared__ float red[4];
  const int m = blockIdx.x, tid = threadIdx.x;
  float x[3];
#pragma unroll
  for (int u = 0; u < 3; ++u) {
    const size_t idx = (size_t)m * 768 + tid + u * 256;
    x[u] = a[idx] + (r ? r[idx] : 0.f);
  }
  const float mean = blk_sum256(x[0] + x[1] + x[2], red) * (1.f / 768.f);
  float lv = 0.f;
#pragma unroll
  for (int u = 0; u < 3; ++u) { float dd = x[u] - mean; lv += dd * dd; }
  const float var = blk_sum256(lv, red) * (1.f / 768.f);
  const float rstd = rsqrtf(var + 1e-5f);
#pragma unroll
  for (int u = 0; u < 3; ++u) {
    const int d = tid + u * 256;
    const float o = (x[u] - mean) * rstd * g[d] + be[d];
    if (outf) outf[(size_t)m * 768 + d] = o;
    if (outb) outb[(size_t)m * 768 + d] = (__bf16)o;
  }
}

// -------- attention: one block per (b,h) ------------------------------------------
__global__ __launch_bounds__(256) void attn_k(const float* __restrict__ qkv,
                                              const int* __restrict__ anum,
                                              __bf16* __restrict__ ctx) {
  __shared__ __bf16 qb[64 * 96], kb[64 * 96], vb[64 * 96];
  __shared__ float sc[64 * 66];
  const int tid = threadIdx.x;
  const int b = blockIdx.x >> 3, h = blockIdx.x & 7;
  const int colq = h * 96;
  for (int idx = tid; idx < 6144; idx += 256) {
    const int s = idx / 96, d = idx - s * 96;
    const size_t base = ((size_t)(b * 64 + s)) * 2304 + colq + d;
    qb[idx] = (__bf16)qkv[base];
    kb[idx] = (__bf16)qkv[base + 768];
    vb[idx] = (__bf16)qkv[base + 1536];
  }
  __syncthreads();
  const int i = tid >> 2, jg = tid & 3;
  for (int jj = 0; jj < 16; ++jj) {
    const int j = jg * 16 + jj;
    float dot = 0.f;
    for (int d = 0; d < 96; ++d) dot += (float)qb[i * 96 + d] * (float)kb[j * 96 + d];
    sc[i * 66 + j] = dot * 0.10206207261596577f;  // 1/sqrt(96)
  }
  __syncthreads();
  if (tid < 64) {
    const int an = anum[b];
    float mx = -3.4e38f;
    for (int j = 0; j < 64; ++j) {
      float v = (j < an) ? sc[tid * 66 + j] : -1e30f;
      sc[tid * 66 + j] = v;
      mx = fmaxf(mx, v);
    }
    float sum = 0.f;
    for (int j = 0; j < 64; ++j) {
      float e = exp2f((sc[tid * 66 + j] - mx) * 1.4426950408889634f);
      sc[tid * 66 + j] = e;
      sum += e;
    }
    const float inv = 1.f / sum;
    for (int j = 0; j < 64; ++j) sc[tid * 66 + j] *= inv;
  }
  __syncthreads();
  const int dg = tid & 3;
  for (int dd = 0; dd < 24; ++dd) {
    const int d = dg * 24 + dd;
    float s2 = 0.f;
    for (int j = 0; j < 64; ++j) s2 += sc[i * 66 + j] * (float)vb[j * 96 + d];
    ctx[((size_t)(b * 64 + i)) * 768 + colq + d] = (__bf16)s2;
  }
}

// -------- row L2-normalize (512-wide) fp32 -> bf16 (for kw) -----------------------
__global__ __launch_bounds__(256) void l2norm_bf16_k(const float* __restrict__ src,
                                                     __bf16* __restrict__ dst) {
  __shared__ float red[4];
  const int rix = blockIdx.x, tid = threadIdx.x;
  const float* row = src + (size_t)rix * 512;
  const float v0 = row[tid], v1 = row[tid + 256];
  const float tot = blk_sum256(v0 * v0 + v1 * v1, red);
  const float inv = 1.f / fmaxf(sqrtf(tot), 1e-8f);
  dst[(size_t)rix * 512 + tid] = (__bf16)(v0 * inv);
  dst[(size_t)rix * 512 + tid + 256] = (__bf16)(v1 * inv);
}

// -------- final: sum split-K slices, scale by 1/rowsum ----------------------------
__global__ __launch_bounds__(256) void final_reduce_k(const float* __restrict__ slices,
                                                      const float* __restrict__ rs,
                                                      float* __restrict__ out) {
  const int m = blockIdx.x, d = threadIdx.x;
  const float inv = 1.f / rs[m];
  float s0 = 0.f, s1 = 0.f;
#pragma unroll
  for (int z = 0; z < ZSL; ++z) {
    const float* sl = slices + (size_t)z * M_ * TD_ + (size_t)m * TD_;
    s0 += sl[d];
    s1 += sl[d + 256];
  }
  out[(size_t)m * TD_ + d] = s0 * inv;
  out[(size_t)m * TD_ + d + 256] = s1 * inv;
}

extern "C" void kernel_launch(void* const* d_in, const int* in_sizes, int n_in,
                              void* d_out, int out_size, void* d_ws, size_t ws_size,
                              hipStream_t stream) {
  const float* audio = (const float*)d_in[0];
  const float* ln1g = (const float*)d_in[1];
  const float* ln1b = (const float*)d_in[2];
  const float* wq = (const float*)d_in[3];
  const float* bq = (const float*)d_in[4];
  const float* wk = (const float*)d_in[5];
  const float* bk = (const float*)d_in[6];
  const float* wv = (const float*)d_in[7];
  const float* bv = (const float*)d_in[8];
  const float* wo = (const float*)d_in[9];
  const float* bo = (const float*)d_in[10];
  const float* lnag = (const float*)d_in[11];
  const float* lnab = (const float*)d_in[12];
  const float* w1 = (const float*)d_in[13];
  const float* b1 = (const float*)d_in[14];
  const float* w2 = (const float*)d_in[15];
  const float* b2 = (const float*)d_in[16];
  const float* lnbg = (const float*)d_in[17];
  const float* lnbb = (const float*)d_in[18];
  const float* wp = (const float*)d_in[19];
  const float* bp = (const float*)d_in[20];
  const float* emb = (const float*)d_in[21];
  const int* alen = (const int*)d_in[22];
  const int* align = (const int*)d_in[23];
  const int* anum = (const int*)d_in[24];
  float* out = (float*)d_out;

  char* p = (char*)d_ws;
  auto alloc = [&](size_t bytes) {
    char* r = p;
    p += (bytes + 255) & ~(size_t)255;
    return r;
  };
  // --- overlay: transformer temporaries (dead by vocab stage) double as kwslice ---
  float* kwslice = (float*)d_ws;
  float* srcsum = (float*)alloc((size_t)M_ * 768 * 4);
  float* srcf = (float*)alloc((size_t)M_ * 768 * 4);
  __bf16* srcb = (__bf16*)alloc((size_t)M_ * 768 * 2);
  float* qkv = (float*)alloc((size_t)M_ * 2304 * 4);
  __bf16* ctxb = (__bf16*)alloc((size_t)M_ * 768 * 2);
  float* ybuf = (float*)alloc((size_t)M_ * 768 * 4);
  float* xf = (float*)alloc((size_t)M_ * 768 * 4);
  __bf16* xb = (__bf16*)alloc((size_t)M_ * 768 * 2);
  __bf16* hb = (__bf16*)alloc((size_t)M_ * FF_ * 2);
  __bf16* x2b = (__bf16*)alloc((size_t)M_ * 768 * 2);
  float* kw = (float*)alloc((size_t)M_ * 512 * 4);
  {  // pad overlay region to >= kwslice size
    const size_t need = (size_t)ZSL * M_ * TD_ * 4;
    const size_t cur = (size_t)(p - (char*)d_ws);
    if (cur < need) alloc(need - cur);
  }
  // --- persistent-through-vocab allocations ---
  __bf16* kwn = (__bf16*)alloc((size_t)M_ * 512 * 2);
  float* rs = (float*)alloc((size_t)M_ * 4);
  __bf16* wqkvT = (__bf16*)alloc((size_t)2304 * 768 * 2);
  __bf16* woT = (__bf16*)alloc((size_t)768 * 768 * 2);
  __bf16* w1T = (__bf16*)alloc((size_t)3072 * 768 * 2);
  __bf16* w2T = (__bf16*)alloc((size_t)768 * 3072 * 2);
  __bf16* wpT = (__bf16*)alloc((size_t)512 * 768 * 2);
  float* bqkv = (float*)alloc((size_t)2304 * 4);

  const size_t used = (size_t)(p - (char*)d_ws);
  const size_t avail = (ws_size > used + 4096) ? (ws_size - used - 4096) : 0;
  const size_t perTile = ((size_t)128 * 512 * 2) * 2 + (size_t)1024 * 128 * 2;
  size_t tp = avail / perTile;
  if (tp < 1) tp = 1;
  if (tp > 386) tp = 386;
  const int tilesPer = (int)tp;
  const int nChunks = (386 + tilesPer - 1) / tilesPer;
  const int maxCols = tilesPer * 128;
  __bf16* embnC = (__bf16*)alloc((size_t)maxCols * 512 * 2);
  __bf16* embTC = (__bf16*)alloc((size_t)512 * maxCols * 2);
  __bf16* Ec = (__bf16*)alloc((size_t)1024 * maxCols * 2);

  hipMemsetAsync(rs, 0, M_ * 4, stream);
  hipMemsetAsync(srcsum, 0, (size_t)M_ * 768 * 4, stream);
  if (nChunks > 1) hipMemsetAsync(kwslice, 0, (size_t)ZSL * M_ * TD_ * 4, stream);

  // weight prep
  transpose_bf16k<<<dim3(24, 24), 256, 0, stream>>>(wq, wqkvT, 768, 768);
  transpose_bf16k<<<dim3(24, 24), 256, 0, stream>>>(wk, wqkvT + (size_t)768 * 768, 768, 768);
  transpose_bf16k<<<dim3(24, 24), 256, 0, stream>>>(wv, wqkvT + (size_t)2 * 768 * 768, 768, 768);
  transpose_bf16k<<<dim3(24, 24), 256, 0, stream>>>(wo, woT, 768, 768);
  transpose_bf16k<<<dim3(96, 24), 256, 0, stream>>>(w1, w1T, 768, 3072);
  transpose_bf16k<<<dim3(24, 96), 256, 0, stream>>>(w2, w2T, 3072, 768);
  transpose_bf16k<<<dim3(16, 24), 256, 0, stream>>>(wp, wpT, 768, 512);
  concat_bias_k<<<9, 256, 0, stream>>>(bq, bk, bv, bqkv);

  // pooling + transformer
  seg_partial_k<<<dim3(16, 16), 256, 0, stream>>>(audio, align, alen, srcsum);
  pool_fin_k<<<M_, 256, 0, stream>>>(srcsum, align, alen, anum, ln1g, ln1b, srcf, srcb);
  gemm_nt<0, 0><<<dim3(8, 18, 1), 256, 0, stream>>>(srcb, wqkvT, bqkv, qkv, 2304, 768, 24);
  attn_k<<<128, 256, 0, stream>>>(qkv, anum, ctxb);
  gemm_nt<0, 0><<<dim3(8, 6, 1), 256, 0, stream>>>(ctxb, woT, bo, ybuf, 768, 768, 24);
  add_ln_k<<<M_, 256, 0, stream>>>(ybuf, srcf, lnag, lnab, xf, xb);
  gemm_nt<1, 0><<<dim3(8, 24, 1), 256, 0, stream>>>(xb, w1T, b1, hb, 3072, 768, 24);
  gemm_nt<0, 0><<<dim3(8, 6, 1), 256, 0, stream>>>(hb, w2T, b2, ybuf, 768, 3072, 96);
  add_ln_k<<<M_, 256, 0, stream>>>(ybuf, xf, lnbg, lnbb, nullptr, x2b);
  gemm_nt<0, 0><<<dim3(8, 4, 1), 256, 0, stream>>>(x2b, wpT, bp, kw, 512, 768, 24);
  l2norm_bf16_k<<<M_, 256, 0, stream>>>(kw, kwn);

  // vocab stage (overlay region dead from here -> kwslice live)
  if (nChunks == 1) {
    embprep_k<<<V_ / 32, 256, 0, stream>>>(emb, embnC, embTC, V_);
    gemm_big_exp<<<4 * 386, 256, 0, stream>>>(kwn, embnC, Ec, rs, V_, 512, 386);
    const int kpz = (V_ / 32 + ZSL - 1) / ZSL;  // 97
    gemm_nt<4, 1><<<dim3(8, 4, ZSL), 256, 0, stream>>>(Ec, embTC, nullptr, kwslice, 512, V_, kpz);
  } else {
    for (int c = 0; c < nChunks; ++c) {
      const int t0 = c * tilesPer;
      const int nt = min(tilesPer, 386 - t0);
      const int v0 = t0 * 128, nc = nt * 128;
      embprep_k<<<nc / 32, 256, 0, stream>>>(emb + (size_t)v0 * 512, embnC, embTC, nc);
      gemm_big_exp<<<4 * nt, 256, 0, stream>>>(kwn, embnC, Ec, rs, nc, 512, nt);
      const int totIt = nc >> 5;
      const int kpz = (totIt + ZSL - 1) / ZSL;
      gemm_nt<5, 1><<<dim3(8, 4, ZSL), 256, 0, stream>>>(Ec, embTC, nullptr, kwslice, 512, nc, kpz);
    }
  }
  final_reduce_k<<<M_, 256, 0, stream>>>(kwslice, rs, out);
}